// Round 3
// baseline (1166.858 us; speedup 1.0000x reference)
//
#include <hip/hip_runtime.h>
#include <math.h>

// Problem constants (fixed by the reference).
constexpr int B_ = 2, T_ = 3, H_ = 128, W_ = 128, C_ = 128;
constexpr int HEADS_ = 8, D_ = 16, CK_ = 128;
constexpr int RY_ = 2, RX_ = 2, PH_ = 5, PW_ = 5, S_ = 25;
constexpr int NTOK = B_ * T_ * H_ * W_;   // 98304 tokens

// ---------------------------------------------------------------------------
// Kernel A: fused QKV projection.
//   kin = values + temp_emb[t];  Q = kin@Wq + q_sp_emb;  K = kin@Wk;  V = values@Wv
// ---------------------------------------------------------------------------
__global__ __launch_bounds__(256) void qkv_proj(
    const float* __restrict__ values, const float* __restrict__ Wq,
    const float* __restrict__ Wk, const float* __restrict__ Wv,
    const float* __restrict__ temp_emb, const float* __restrict__ spatial_emb,
    float* __restrict__ Qo, float* __restrict__ Ko, float* __restrict__ Vo)
{
    __shared__ float kin_s[16][128];
    __shared__ float val_s[16][128];
    const int tok0 = blockIdx.x * 16;

    for (int i = threadIdx.x; i < 16 * 128; i += 256) {
        const int tk = i >> 7, c = i & 127;
        const int tok = tok0 + tk;
        const int t = (tok >> 14) % T_;           // H*W = 16384 = 1<<14
        const float v = values[(size_t)tok * C_ + c];
        val_s[tk][c] = v;
        kin_s[tk][c] = v + temp_emb[t * C_ + c];
    }
    __syncthreads();

    const int wave = threadIdx.x >> 6, lane = threadIdx.x & 63;
    const int tbase = wave * 4;

    float aQ[4][2] = {}, aK[4][2] = {}, aV[4][2] = {};

    for (int c = 0; c < 128; c += 4) {
        float kcf[16], vcf[16];
#pragma unroll
        for (int j = 0; j < 4; ++j) {
            *(float4*)&kcf[j * 4] = *(const float4*)&kin_s[tbase + j][c];
            *(float4*)&vcf[j * 4] = *(const float4*)&val_s[tbase + j][c];
        }
#pragma unroll
        for (int cc = 0; cc < 4; ++cc) {
            const float wq0 = Wq[(c + cc) * 128 + lane];
            const float wq1 = Wq[(c + cc) * 128 + lane + 64];
            const float wk0 = Wk[(c + cc) * 128 + lane];
            const float wk1 = Wk[(c + cc) * 128 + lane + 64];
            const float wv0 = Wv[(c + cc) * 128 + lane];
            const float wv1 = Wv[(c + cc) * 128 + lane + 64];
#pragma unroll
            for (int j = 0; j < 4; ++j) {
                const float kv = kcf[j * 4 + cc];
                const float vv = vcf[j * 4 + cc];
                aQ[j][0] += kv * wq0; aQ[j][1] += kv * wq1;
                aK[j][0] += kv * wk0; aK[j][1] += kv * wk1;
                aV[j][0] += vv * wv0; aV[j][1] += vv * wv1;
            }
        }
    }

#pragma unroll
    for (int j = 0; j < 4; ++j) {
        const int tok = tok0 + tbase + j;
        const int x = tok & 127, y = (tok >> 7) & 127;
        const int cy = min(max(y, RY_), H_ - 1 - RY_);
        const int cx = min(max(x, RX_), W_ - 1 - RX_);
        const int qsp = (y - cy + RY_) * PW_ + (x - cx + RX_);
        const size_t o = (size_t)tok * CK_;
        Qo[o + lane]      = aQ[j][0] + spatial_emb[qsp * CK_ + lane];
        Qo[o + lane + 64] = aQ[j][1] + spatial_emb[qsp * CK_ + lane + 64];
        Ko[o + lane]      = aK[j][0];
        Ko[o + lane + 64] = aK[j][1];
        Vo[o + lane]      = aV[j][0];
        Vo[o + lane + 64] = aV[j][1];
    }
}

// ---------------------------------------------------------------------------
// Kernel B: attention, head-per-lane layout. lane = tsub*8 + head: each lane
// owns the full D=16 channels of one (token, head) -> dot product is entirely
// lane-local, NO cross-lane shuffles. 8 tokens per wave, 32 per block.
// q*(k+e) is split as q*k + (q*e) with qe[s] precomputed once per token
// (spatial_emb staged in LDS), removing the emb add from the inner loop.
// Plain exp2 softmax (scores bounded by construction, verified R1/R2).
// ---------------------------------------------------------------------------
__global__ __launch_bounds__(256) void attn_ck(
    const float* __restrict__ Q, const float* __restrict__ K,
    const float* __restrict__ V, const float* __restrict__ spatial_emb,
    float* __restrict__ ck)
{
    __shared__ float sp_s[S_][CK_];   // 12.8 KB
    for (int i = threadIdx.x; i < S_ * CK_; i += 256)
        ((float*)sp_s)[i] = spatial_emb[i];

    const int wave = threadIdx.x >> 6, lane = threadIdx.x & 63;
    const int tsub = lane >> 3, head = lane & 7;
    const int tok = blockIdx.x * 32 + wave * 8 + tsub;
    const int ch0 = head * 16;
    const int x = tok & 127, y = (tok >> 7) & 127;
    const int b = (tok >> 14) / T_;

    constexpr float CSC = 0.25f * 1.44269504088896f;  // scale * log2(e)
    float q[16];
    {
        const float4* qp = (const float4*)&Q[(size_t)tok * CK_ + ch0];
#pragma unroll
        for (int j = 0; j < 4; ++j) {
            const float4 t = qp[j];
            q[4 * j + 0] = t.x * CSC; q[4 * j + 1] = t.y * CSC;
            q[4 * j + 2] = t.z * CSC; q[4 * j + 3] = t.w * CSC;
        }
    }
    __syncthreads();

    // qe[s] = (scaled q) . spatial_emb[s]
    float qe[S_];
#pragma unroll
    for (int s = 0; s < S_; ++s) {
        const float4* ep = (const float4*)&sp_s[s][ch0];
        float acc = 0.f;
#pragma unroll
        for (int j = 0; j < 4; ++j) {
            const float4 e = ep[j];
            acc += q[4 * j] * e.x + q[4 * j + 1] * e.y
                 + q[4 * j + 2] * e.z + q[4 * j + 3] * e.w;
        }
        qe[s] = acc;
    }

    const int cy = min(max(y, RY_), H_ - 1 - RY_);
    const int cx = min(max(x, RX_), W_ - 1 - RX_);
    const size_t tstr = (size_t)H_ * W_ * CK_;

    float l = 0.f;
    float o[16] = {};

    for (int s = 0; s < S_; ++s) {
        const int ny = min(max(cy + s / PW_ - RY_, 0), H_ - 1);
        const int nx = min(max(cx + s % PW_ - RX_, 0), W_ - 1);
        const size_t base = ((((size_t)b * T_) * H_ + ny) * W_ + nx) * CK_ + ch0;
#pragma unroll
        for (int t = 0; t < T_; ++t) {
            const float4* kp = (const float4*)&K[base + (size_t)t * tstr];
            const float4* vp = (const float4*)&V[base + (size_t)t * tstr];
            const float4 k0 = kp[0], k1 = kp[1], k2 = kp[2], k3 = kp[3];
            const float4 v0 = vp[0], v1 = vp[1], v2 = vp[2], v3 = vp[3];
            float d = qe[s];
            d += q[0]  * k0.x + q[1]  * k0.y + q[2]  * k0.z + q[3]  * k0.w;
            d += q[4]  * k1.x + q[5]  * k1.y + q[6]  * k1.z + q[7]  * k1.w;
            d += q[8]  * k2.x + q[9]  * k2.y + q[10] * k2.z + q[11] * k2.w;
            d += q[12] * k3.x + q[13] * k3.y + q[14] * k3.z + q[15] * k3.w;
            const float p = __builtin_amdgcn_exp2f(d);
            l += p;
            o[0]  += p * v0.x; o[1]  += p * v0.y; o[2]  += p * v0.z; o[3]  += p * v0.w;
            o[4]  += p * v1.x; o[5]  += p * v1.y; o[6]  += p * v1.z; o[7]  += p * v1.w;
            o[8]  += p * v2.x; o[9]  += p * v2.y; o[10] += p * v2.z; o[11] += p * v2.w;
            o[12] += p * v3.x; o[13] += p * v3.y; o[14] += p * v3.z; o[15] += p * v3.w;
        }
    }

    const float inv = __builtin_amdgcn_rcpf(l);
    float4* op = (float4*)&ck[(size_t)tok * CK_ + ch0];
#pragma unroll
    for (int j = 0; j < 4; ++j) {
        float4 t;
        t.x = o[4 * j + 0] * inv; t.y = o[4 * j + 1] * inv;
        t.z = o[4 * j + 2] * inv; t.w = o[4 * j + 3] * inv;
        op[j] = t;
    }
}

// ---------------------------------------------------------------------------
// Kernel C: out = ck @ Wo, in-place on d_out (block reads its 16 tokens into
// LDS before any write, so in-place is race-free).
// ---------------------------------------------------------------------------
__global__ __launch_bounds__(256) void out_proj(
    const float* __restrict__ Wo, float* __restrict__ io)
{
    __shared__ float ck_s[16][128];
    const int tok0 = blockIdx.x * 16;

    for (int i = threadIdx.x; i < 16 * 128; i += 256) {
        const int tk = i >> 7, c = i & 127;
        ck_s[tk][c] = io[(size_t)(tok0 + tk) * C_ + c];
    }
    __syncthreads();

    const int wave = threadIdx.x >> 6, lane = threadIdx.x & 63;
    const int tbase = wave * 4;
    float acc[4][2] = {};

    for (int c = 0; c < 128; c += 4) {
        float cf[16];
#pragma unroll
        for (int j = 0; j < 4; ++j)
            *(float4*)&cf[j * 4] = *(const float4*)&ck_s[tbase + j][c];
#pragma unroll
        for (int cc = 0; cc < 4; ++cc) {
            const float w0 = Wo[(c + cc) * 128 + lane];
            const float w1 = Wo[(c + cc) * 128 + lane + 64];
#pragma unroll
            for (int j = 0; j < 4; ++j) {
                acc[j][0] += cf[j * 4 + cc] * w0;
                acc[j][1] += cf[j * 4 + cc] * w1;
            }
        }
    }

#pragma unroll
    for (int j = 0; j < 4; ++j) {
        const size_t o = (size_t)(tok0 + tbase + j) * C_;
        io[o + lane]      = acc[j][0];
        io[o + lane + 64] = acc[j][1];
    }
}

// ---------------------------------------------------------------------------
extern "C" void kernel_launch(void* const* d_in, const int* in_sizes, int n_in,
                              void* d_out, int out_size, void* d_ws, size_t ws_size,
                              hipStream_t stream) {
    const float* values      = (const float*)d_in[0];
    const float* Wq          = (const float*)d_in[1];
    const float* Wk          = (const float*)d_in[2];
    const float* Wv          = (const float*)d_in[3];
    const float* Wo          = (const float*)d_in[4];
    const float* temp_emb    = (const float*)d_in[5];
    const float* spatial_emb = (const float*)d_in[6];
    float* out = (float*)d_out;

    float* Qb = (float*)d_ws;
    float* Kb = Qb + (size_t)NTOK * CK_;
    float* Vb = Kb + (size_t)NTOK * CK_;

    qkv_proj<<<NTOK / 16, 256, 0, stream>>>(values, Wq, Wk, Wv, temp_emb,
                                            spatial_emb, Qb, Kb, Vb);
    attn_ck<<<NTOK / 32, 256, 0, stream>>>(Qb, Kb, Vb, spatial_emb, out);
    out_proj<<<NTOK / 16, 256, 0, stream>>>(Wo, out);
}

// Round 5
// 493.723 us; speedup vs baseline: 2.3634x; 2.3634x over previous
//
#include <hip/hip_runtime.h>
#include <math.h>

// Problem constants (fixed by the reference).
constexpr int B_ = 2, T_ = 3, H_ = 128, W_ = 128, C_ = 128;
constexpr int HEADS_ = 8, D_ = 16, CK_ = 128;
constexpr int RY_ = 2, RX_ = 2, PH_ = 5, PW_ = 5, S_ = 25;
constexpr int NTOK = B_ * T_ * H_ * W_;   // 98304 tokens

typedef float     f32x4 __attribute__((ext_vector_type(4)));
typedef _Float16  f16x4 __attribute__((ext_vector_type(4)));

static __device__ __forceinline__ f32x4 mfma16(f16x4 a, f16x4 b, f32x4 c) {
#if __has_builtin(__builtin_amdgcn_mfma_f32_16x16x16f16)
  return __builtin_amdgcn_mfma_f32_16x16x16f16(a, b, c, 0, 0, 0);
#else
  asm volatile("v_mfma_f32_16x16x16_f16 %0, %1, %2, %0" : "+v"(c) : "v"(a), "v"(b));
  return c;
#endif
}

// ---------------------------------------------------------------------------
// Kernel A: fused QKV projection (unchanged — known good).
// ---------------------------------------------------------------------------
__global__ __launch_bounds__(256) void qkv_proj(
    const float* __restrict__ values, const float* __restrict__ Wq,
    const float* __restrict__ Wk, const float* __restrict__ Wv,
    const float* __restrict__ temp_emb, const float* __restrict__ spatial_emb,
    float* __restrict__ Qo, float* __restrict__ Ko, float* __restrict__ Vo)
{
    __shared__ float kin_s[16][128];
    __shared__ float val_s[16][128];
    const int tok0 = blockIdx.x * 16;

    for (int i = threadIdx.x; i < 16 * 128; i += 256) {
        const int tk = i >> 7, c = i & 127;
        const int tok = tok0 + tk;
        const int t = (tok >> 14) % T_;
        const float v = values[(size_t)tok * C_ + c];
        val_s[tk][c] = v;
        kin_s[tk][c] = v + temp_emb[t * C_ + c];
    }
    __syncthreads();

    const int wave = threadIdx.x >> 6, lane = threadIdx.x & 63;
    const int tbase = wave * 4;

    float aQ[4][2] = {}, aK[4][2] = {}, aV[4][2] = {};

    for (int c = 0; c < 128; c += 4) {
        float kcf[16], vcf[16];
#pragma unroll
        for (int j = 0; j < 4; ++j) {
            *(float4*)&kcf[j * 4] = *(const float4*)&kin_s[tbase + j][c];
            *(float4*)&vcf[j * 4] = *(const float4*)&val_s[tbase + j][c];
        }
#pragma unroll
        for (int cc = 0; cc < 4; ++cc) {
            const float wq0 = Wq[(c + cc) * 128 + lane];
            const float wq1 = Wq[(c + cc) * 128 + lane + 64];
            const float wk0 = Wk[(c + cc) * 128 + lane];
            const float wk1 = Wk[(c + cc) * 128 + lane + 64];
            const float wv0 = Wv[(c + cc) * 128 + lane];
            const float wv1 = Wv[(c + cc) * 128 + lane + 64];
#pragma unroll
            for (int j = 0; j < 4; ++j) {
                const float kv = kcf[j * 4 + cc];
                const float vv = vcf[j * 4 + cc];
                aQ[j][0] += kv * wq0; aQ[j][1] += kv * wq1;
                aK[j][0] += kv * wk0; aK[j][1] += kv * wk1;
                aV[j][0] += vv * wv0; aV[j][1] += vv * wv1;
            }
        }
    }

#pragma unroll
    for (int j = 0; j < 4; ++j) {
        const int tok = tok0 + tbase + j;
        const int x = tok & 127, y = (tok >> 7) & 127;
        const int cy = min(max(y, RY_), H_ - 1 - RY_);
        const int cx = min(max(x, RX_), W_ - 1 - RX_);
        const int qsp = (y - cy + RY_) * PW_ + (x - cx + RX_);
        const size_t o = (size_t)tok * CK_;
        Qo[o + lane]      = aQ[j][0] + spatial_emb[qsp * CK_ + lane];
        Qo[o + lane + 64] = aQ[j][1] + spatial_emb[qsp * CK_ + lane + 64];
        Ko[o + lane]      = aK[j][0];
        Ko[o + lane + 64] = aK[j][1];
        Vo[o + lane]      = aV[j][0];
        Vo[o + lane + 64] = aV[j][1];
    }
}

// ---------------------------------------------------------------------------
// Kernel B: MFMA attention, fp16. Block = (8x8 query tile) x (4-head half).
// K region [12 rows x 16 cols] staged per frame: K [192][68], then V^T
// [64][196] in same buffer. S^T = K.Q^T (N-tile == region row); mask+bias+
// exp2 in C-regs; C-frag lane layout == B-frag layout => w feeds PV MFMA
// (o^T = V^T.w^T) directly from registers. Q.emb_s bias via 8 MFMAs into a
// per-block qe table (f16 LDS), read with PER-ELEMENT clamped s index.
// ---------------------------------------------------------------------------
__global__ __launch_bounds__(256) void attn_mfma(
    const float* __restrict__ Q, const float* __restrict__ K,
    const float* __restrict__ V, const float* __restrict__ spatial_emb,
    float* __restrict__ ck)
{
  __shared__ __align__(16) _Float16 kv_s[192 * 68];   // K / V^T / emb
  __shared__ __align__(16) _Float16 qe_s[4 * 32 * 64]; // [4h][32s][64q]

  const int tid = threadIdx.x;
  const int bid = blockIdx.x;
  const int hh   = bid & 1;            // head half: ch base hh*64
  const int tile = bid >> 1;
  const int tx = tile & 15, ty = (tile >> 4) & 15, img = tile >> 8; // img = b*3+qf
  const int b = img / 3;
  const int y0 = ty * 8, x0 = tx * 8;
  const int rowbase = max(y0, 2) - 2;
  const int colbase = max(x0, 2) - 2;
  const int tokbase = img * 16384 + y0 * 128 + x0;

  const int l   = tid & 63;
  const int wv  = tid >> 6;
  const int l15 = l & 15;
  const int g   = l >> 4;

  const int q_glob = wv * 16 + l15;
  const int qy = 2 * wv + (l15 >> 3);
  const int qx = l15 & 7;
  const int y = y0 + qy, x = x0 + qx;
  const int tok = tokbase + qy * 128 + qx;
  const int cy = min(max(y, 2), 125), cx = min(max(x, 2), 125);
  const int myryc = cy - rowbase;
  const int rxc   = cx - colbase;
  const int dxpbase = 4 * g - rxc + 2;

  // wave-uniform valid-row window start (always covers [rymin, rymin+5])
  const int rycA = min(max(y0 + 2 * wv,     2), 125) - rowbase;
  const int rycB = min(max(y0 + 2 * wv + 1, 2), 125) - rowbase;
  const int rymin = min(min(rycA, rycB) - 2, 6);   // >= 0 by construction

  constexpr float CSC = 0.25f * 1.44269504088896f;  // scale * log2(e)

  // ---- stage emb rows (zero rows 25..31) ----
  for (int idx = tid; idx < 32 * 16; idx += 256) {
    const int s = idx >> 4, cg = idx & 15;
    f16x4 ep = {(_Float16)0.f, (_Float16)0.f, (_Float16)0.f, (_Float16)0.f};
    if (s < 25) {
      const float4 e = *(const float4*)&spatial_emb[s * CK_ + hh * 64 + cg * 4];
      ep[0] = (_Float16)e.x; ep[1] = (_Float16)e.y;
      ep[2] = (_Float16)e.z; ep[3] = (_Float16)e.w;
    }
    *(f16x4*)&kv_s[s * 68 + cg * 4] = ep;
  }

  // ---- Q fragments (pre-scaled) ----
  f16x4 qfrag[4];
#pragma unroll
  for (int h = 0; h < 4; ++h) {
    const float4 qv = *(const float4*)&Q[(size_t)tok * CK_ + (hh * 4 + h) * 16 + 4 * g];
    qfrag[h][0] = (_Float16)(qv.x * CSC); qfrag[h][1] = (_Float16)(qv.y * CSC);
    qfrag[h][2] = (_Float16)(qv.z * CSC); qfrag[h][3] = (_Float16)(qv.w * CSC);
  }
  __syncthreads();

  // ---- qe[s][q] = (scaled Q) . emb_s via MFMA ----
#pragma unroll
  for (int h = 0; h < 4; ++h) {
#pragma unroll
    for (int mt = 0; mt < 2; ++mt) {
      const f16x4 a = *(const f16x4*)&kv_s[(mt * 16 + l15) * 68 + h * 16 + 4 * g];
      f32x4 c = {0.f, 0.f, 0.f, 0.f};
      c = mfma16(a, qfrag[h], c);
#pragma unroll
      for (int i = 0; i < 4; ++i) {
        const int s = mt * 16 + 4 * g + i;
        qe_s[h * 2048 + s * 64 + q_glob] = (_Float16)c[i];
      }
    }
  }

  f32x4 o_acc[4];
  float l_acc[4];
#pragma unroll
  for (int h = 0; h < 4; ++h) { o_acc[h] = (f32x4){0.f, 0.f, 0.f, 0.f}; l_acc[h] = 0.f; }

  f16x4 w_frags[4][6];
  const float NEGBIG = -1.0e30f;

  for (int t = 0; t < 3; ++t) {
    __syncthreads();   // qe_s written / prev PV done before overwriting kv_s

    // ---- stage K (frame t): [192 keys][68] f16 ----
    const int kimgbase = (b * 3 + t) * 16384;
    for (int idx = tid; idx < 192 * 16; idx += 256) {
      const int key = idx >> 4, cg = idx & 15;
      const int ny = min(rowbase + (key >> 4), 127);
      const int nx = min(colbase + (key & 15), 127);
      const float4 k4 = *(const float4*)&K[((size_t)(kimgbase + ny * 128 + nx)) * CK_ + hh * 64 + cg * 4];
      f16x4 kp;
      kp[0] = (_Float16)k4.x; kp[1] = (_Float16)k4.y;
      kp[2] = (_Float16)k4.z; kp[3] = (_Float16)k4.w;
      *(f16x4*)&kv_s[key * 68 + cg * 4] = kp;
    }
    __syncthreads();

    // ---- scores: S^T = K . Q^T ; mask+bias+exp2 ; build w fragments ----
#pragma unroll
    for (int h = 0; h < 4; ++h) {
#pragma unroll
      for (int jj = 0; jj < 6; ++jj) {
        const int nt = rymin + jj;
        const f16x4 a = *(const f16x4*)&kv_s[(nt * 16 + l15) * 68 + h * 16 + 4 * g];
        f32x4 c = {0.f, 0.f, 0.f, 0.f};
        c = mfma16(a, qfrag[h], c);
        const int dyp = nt - myryc + 2;                 // per-lane (query row)
        const bool vy = (unsigned)dyp <= 4u;
        const int s0 = dyp * 5 + dxpbase;
        const int qbase = h * 2048 + q_glob;
        float p0, p1, p2, p3;
#pragma unroll
        for (int i = 0; i < 4; ++i) {
          const int si = min(max(s0 + i, 0), 31);       // per-element clamp
          const float qv = (float)qe_s[qbase + si * 64];
          float sc = c[i] + qv;
          const bool vi = vy && ((unsigned)(dxpbase + i) <= 4u);
          sc = vi ? sc : NEGBIG;
          const float p = __builtin_amdgcn_exp2f(sc);
          l_acc[h] += p;
          if (i == 0) p0 = p; else if (i == 1) p1 = p; else if (i == 2) p2 = p; else p3 = p;
        }
        f16x4 wf;
        wf[0] = (_Float16)p0; wf[1] = (_Float16)p1;
        wf[2] = (_Float16)p2; wf[3] = (_Float16)p3;
        w_frags[h][jj] = wf;
      }
    }
    __syncthreads();   // all waves done reading K

    // ---- stage V^T (frame t): [64 ch][196] f16 ----
    for (int idx = tid; idx < 192 * 16; idx += 256) {
      const int key = idx >> 4, cg = idx & 15;
      const int ny = min(rowbase + (key >> 4), 127);
      const int nx = min(colbase + (key & 15), 127);
      const float4 v4 = *(const float4*)&V[((size_t)(kimgbase + ny * 128 + nx)) * CK_ + hh * 64 + cg * 4];
      kv_s[(cg * 4    ) * 196 + key] = (_Float16)v4.x;
      kv_s[(cg * 4 + 1) * 196 + key] = (_Float16)v4.y;
      kv_s[(cg * 4 + 2) * 196 + key] = (_Float16)v4.z;
      kv_s[(cg * 4 + 3) * 196 + key] = (_Float16)v4.w;
    }
    __syncthreads();

    // ---- PV: o^T += V^T . w^T ----
#pragma unroll
    for (int h = 0; h < 4; ++h) {
#pragma unroll
      for (int jj = 0; jj < 6; ++jj) {
        const int nt = rymin + jj;
        const f16x4 a = *(const f16x4*)&kv_s[(h * 16 + l15) * 196 + nt * 16 + 4 * g];
        o_acc[h] = mfma16(a, w_frags[h][jj], o_acc[h]);
      }
    }
  }

  // ---- normalize + store ----
#pragma unroll
  for (int h = 0; h < 4; ++h) {
    float lt = l_acc[h];
    lt += __shfl_xor(lt, 16);
    lt += __shfl_xor(lt, 32);
    const float inv = 1.f / lt;
    float4 ov;
    ov.x = o_acc[h][0] * inv; ov.y = o_acc[h][1] * inv;
    ov.z = o_acc[h][2] * inv; ov.w = o_acc[h][3] * inv;
    *(float4*)&ck[(size_t)tok * CK_ + (hh * 4 + h) * 16 + 4 * g] = ov;
  }
}

// ---------------------------------------------------------------------------
// Kernel C: out = ck @ Wo, in-place on d_out.
// ---------------------------------------------------------------------------
__global__ __launch_bounds__(256) void out_proj(
    const float* __restrict__ Wo, float* __restrict__ io)
{
    __shared__ float ck_s[16][128];
    const int tok0 = blockIdx.x * 16;

    for (int i = threadIdx.x; i < 16 * 128; i += 256) {
        const int tk = i >> 7, c = i & 127;
        ck_s[tk][c] = io[(size_t)(tok0 + tk) * C_ + c];
    }
    __syncthreads();

    const int wave = threadIdx.x >> 6, lane = threadIdx.x & 63;
    const int tbase = wave * 4;
    float acc[4][2] = {};

    for (int c = 0; c < 128; c += 4) {
        float cf[16];
#pragma unroll
        for (int j = 0; j < 4; ++j)
            *(float4*)&cf[j * 4] = *(const float4*)&ck_s[tbase + j][c];
#pragma unroll
        for (int cc = 0; cc < 4; ++cc) {
            const float w0 = Wo[(c + cc) * 128 + lane];
            const float w1 = Wo[(c + cc) * 128 + lane + 64];
#pragma unroll
            for (int j = 0; j < 4; ++j) {
                acc[j][0] += cf[j * 4 + cc] * w0;
                acc[j][1] += cf[j * 4 + cc] * w1;
            }
        }
    }

#pragma unroll
    for (int j = 0; j < 4; ++j) {
        const size_t o = (size_t)(tok0 + tbase + j) * C_;
        io[o + lane]      = acc[j][0];
        io[o + lane + 64] = acc[j][1];
    }
}

// ---------------------------------------------------------------------------
extern "C" void kernel_launch(void* const* d_in, const int* in_sizes, int n_in,
                              void* d_out, int out_size, void* d_ws, size_t ws_size,
                              hipStream_t stream) {
    const float* values      = (const float*)d_in[0];
    const float* Wq          = (const float*)d_in[1];
    const float* Wk          = (const float*)d_in[2];
    const float* Wv          = (const float*)d_in[3];
    const float* Wo          = (const float*)d_in[4];
    const float* temp_emb    = (const float*)d_in[5];
    const float* spatial_emb = (const float*)d_in[6];
    float* out = (float*)d_out;

    float* Qb = (float*)d_ws;
    float* Kb = Qb + (size_t)NTOK * CK_;
    float* Vb = Kb + (size_t)NTOK * CK_;

    qkv_proj<<<NTOK / 16, 256, 0, stream>>>(values, Wq, Wk, Wv, temp_emb,
                                            spatial_emb, Qb, Kb, Vb);
    // grid = 2 head-halves x (2 B x 3 Tq x 16 x 16 tiles) = 3072 blocks
    attn_mfma<<<3072, 256, 0, stream>>>(Qb, Kb, Vb, spatial_emb, out);
    out_proj<<<NTOK / 16, 256, 0, stream>>>(Wo, out);
}

// Round 6
// 444.873 us; speedup vs baseline: 2.6229x; 1.1098x over previous
//
#include <hip/hip_runtime.h>
#include <math.h>

// Problem constants (fixed by the reference).
constexpr int B_ = 2, T_ = 3, H_ = 128, W_ = 128, C_ = 128;
constexpr int HEADS_ = 8, D_ = 16, CK_ = 128;
constexpr int RY_ = 2, RX_ = 2, PH_ = 5, PW_ = 5, S_ = 25;
constexpr int NTOK = B_ * T_ * H_ * W_;   // 98304 tokens

typedef float     f32x4 __attribute__((ext_vector_type(4)));
typedef _Float16  f16x4 __attribute__((ext_vector_type(4)));

static __device__ __forceinline__ f32x4 mfma16(f16x4 a, f16x4 b, f32x4 c) {
#if __has_builtin(__builtin_amdgcn_mfma_f32_16x16x16f16)
  return __builtin_amdgcn_mfma_f32_16x16x16f16(a, b, c, 0, 0, 0);
#else
  asm volatile("v_mfma_f32_16x16x16_f16 %0, %1, %2, %0" : "+v"(c) : "v"(a), "v"(b));
  return c;
#endif
}

// ---------------------------------------------------------------------------
// Kernel P: pack weights to fp16 TRANSPOSED ([n][k], so MFMA A-frags are
// contiguous) and spatial_emb to fp16 zero-padded [32][128].
// ---------------------------------------------------------------------------
__global__ __launch_bounds__(256) void prep(
    const float* __restrict__ Wq, const float* __restrict__ Wk,
    const float* __restrict__ Wv, const float* __restrict__ Wo,
    const float* __restrict__ sp,
    _Float16* __restrict__ WqT, _Float16* __restrict__ WkT,
    _Float16* __restrict__ WvT, _Float16* __restrict__ WoT,
    _Float16* __restrict__ spH)
{
  const int idx = blockIdx.x * 256 + threadIdx.x;
  if (idx < 16384) {
    const int n = idx >> 7, k = idx & 127;
    WqT[idx] = (_Float16)Wq[k * 128 + n];
  } else if (idx < 32768) {
    const int j = idx - 16384; const int n = j >> 7, k = j & 127;
    WkT[j] = (_Float16)Wk[k * 128 + n];
  } else if (idx < 49152) {
    const int j = idx - 32768; const int n = j >> 7, k = j & 127;
    WvT[j] = (_Float16)Wv[k * 128 + n];
  } else if (idx < 65536) {
    const int j = idx - 49152; const int n = j >> 7, k = j & 127;
    WoT[j] = (_Float16)Wo[k * 128 + n];
  } else if (idx < 69632) {
    const int j = idx - 65536; const int s = j >> 7, c = j & 127;
    spH[j] = (s < 25) ? (_Float16)sp[s * 128 + c] : (_Float16)0.f;
  }
}

// ---------------------------------------------------------------------------
// Kernel A: QKV projection via MFMA. Block = 64 tokens, 4 waves (16 tok each).
// kin/val staged fp16 in LDS [64][132] (pad -> conflict-free b64 reads).
// Per wave: 8 K-chunks x 24 N-tiles of mfma_f32_16x16x16_f16.
// Q output is pre-scaled by 0.25*log2(e) and has q_sp_emb folded in.
// ---------------------------------------------------------------------------
__global__ __launch_bounds__(256) void qkv_mfma(
    const float* __restrict__ values, const _Float16* __restrict__ WqT,
    const _Float16* __restrict__ WkT, const _Float16* __restrict__ WvT,
    const float* __restrict__ temp_emb, const float* __restrict__ spatial_emb,
    _Float16* __restrict__ Qh, _Float16* __restrict__ Kh, _Float16* __restrict__ Vh)
{
  __shared__ __align__(16) _Float16 kin_s[64][132];
  __shared__ __align__(16) _Float16 val_s[64][132];
  const int tid = threadIdx.x;
  const int tok0 = blockIdx.x * 64;

  for (int i = tid; i < 64 * 32; i += 256) {      // i: (token, 4-ch group)
    const int tk = i >> 5, cg = i & 31;
    const int tok = tok0 + tk;
    const int t = (tok >> 14) % T_;
    const float4 v  = *(const float4*)&values[(size_t)tok * C_ + cg * 4];
    const float4 te = *(const float4*)&temp_emb[t * C_ + cg * 4];
    f16x4 kv, vv;
    vv[0] = (_Float16)v.x; vv[1] = (_Float16)v.y;
    vv[2] = (_Float16)v.z; vv[3] = (_Float16)v.w;
    kv[0] = (_Float16)(v.x + te.x); kv[1] = (_Float16)(v.y + te.y);
    kv[2] = (_Float16)(v.z + te.z); kv[3] = (_Float16)(v.w + te.w);
    *(f16x4*)&kin_s[tk][cg * 4] = kv;
    *(f16x4*)&val_s[tk][cg * 4] = vv;
  }
  __syncthreads();

  const int l = tid & 63, wv = tid >> 6, l15 = l & 15, g = l >> 4;

  f32x4 acc[24];
#pragma unroll
  for (int i = 0; i < 24; ++i) acc[i] = (f32x4){0.f, 0.f, 0.f, 0.f};

  for (int kc = 0; kc < 8; ++kc) {
    const f16x4 bk = *(const f16x4*)&kin_s[wv * 16 + l15][kc * 16 + 4 * g];
    const f16x4 bv = *(const f16x4*)&val_s[wv * 16 + l15][kc * 16 + 4 * g];
    const int ko = kc * 16 + 4 * g;
#pragma unroll
    for (int nt = 0; nt < 8; ++nt) {
      const f16x4 a = *(const f16x4*)&WqT[(nt * 16 + l15) * 128 + ko];
      acc[nt] = mfma16(a, bk, acc[nt]);
    }
#pragma unroll
    for (int nt = 0; nt < 8; ++nt) {
      const f16x4 a = *(const f16x4*)&WkT[(nt * 16 + l15) * 128 + ko];
      acc[8 + nt] = mfma16(a, bk, acc[8 + nt]);
    }
#pragma unroll
    for (int nt = 0; nt < 8; ++nt) {
      const f16x4 a = *(const f16x4*)&WvT[(nt * 16 + l15) * 128 + ko];
      acc[16 + nt] = mfma16(a, bv, acc[16 + nt]);
    }
  }

  // epilogue: lane holds D[ch = nt*16+4g+i][tok = tok0+wv*16+l15]
  constexpr float CSC = 0.25f * 1.44269504088896f;
  const int tok = tok0 + wv * 16 + l15;
  const int x = tok & 127, y = (tok >> 7) & 127;
  const int cy = min(max(y, RY_), H_ - 1 - RY_);
  const int cx = min(max(x, RX_), W_ - 1 - RX_);
  const int qsp = (y - cy + RY_) * PW_ + (x - cx + RX_);
#pragma unroll
  for (int nt = 0; nt < 8; ++nt) {
    const int ch = nt * 16 + 4 * g;
    const float4 e = *(const float4*)&spatial_emb[qsp * CK_ + ch];
    f16x4 q, k, v;
    q[0] = (_Float16)((acc[nt][0] + e.x) * CSC);
    q[1] = (_Float16)((acc[nt][1] + e.y) * CSC);
    q[2] = (_Float16)((acc[nt][2] + e.z) * CSC);
    q[3] = (_Float16)((acc[nt][3] + e.w) * CSC);
    k[0] = (_Float16)acc[8 + nt][0]; k[1] = (_Float16)acc[8 + nt][1];
    k[2] = (_Float16)acc[8 + nt][2]; k[3] = (_Float16)acc[8 + nt][3];
    v[0] = (_Float16)acc[16 + nt][0]; v[1] = (_Float16)acc[16 + nt][1];
    v[2] = (_Float16)acc[16 + nt][2]; v[3] = (_Float16)acc[16 + nt][3];
    const size_t o = (size_t)tok * CK_ + ch;
    *(f16x4*)&Qh[o] = q;
    *(f16x4*)&Kh[o] = k;
    *(f16x4*)&Vh[o] = v;
  }
}

// ---------------------------------------------------------------------------
// Kernel B: MFMA attention, fp16 in/out. Block = (8x8 query tile) x head-half.
// K [192][72] then V^T [64][200] staged in same LDS (padded strides chosen so
// b64 reads hit distinct bank-pairs). qe table [4][32][68] (stride 68 spreads
// the per-element scalar reads across banks). emb A-frags read from global.
// ---------------------------------------------------------------------------
__global__ __launch_bounds__(256) void attn_mfma(
    const _Float16* __restrict__ Q, const _Float16* __restrict__ K,
    const _Float16* __restrict__ V, const _Float16* __restrict__ spH,
    _Float16* __restrict__ ck)
{
  __shared__ __align__(16) _Float16 kv_s[13824];       // K [192][72] / V^T [64][200]
  __shared__ __align__(16) _Float16 qe_s[4 * 32 * 68]; // [4h][32s][68]

  const int tid = threadIdx.x;
  const int bid = blockIdx.x;
  const int hh   = bid & 1;
  const int tile = bid >> 1;
  const int tx = tile & 15, ty = (tile >> 4) & 15, img = tile >> 8;
  const int b = img / 3;
  const int y0 = ty * 8, x0 = tx * 8;
  const int rowbase = max(y0, 2) - 2;
  const int colbase = max(x0, 2) - 2;
  const int tokbase = img * 16384 + y0 * 128 + x0;

  const int l   = tid & 63;
  const int wv  = tid >> 6;
  const int l15 = l & 15;
  const int g   = l >> 4;

  const int q_glob = wv * 16 + l15;
  const int qy = 2 * wv + (l15 >> 3);
  const int qx = l15 & 7;
  const int y = y0 + qy, x = x0 + qx;
  const int tok = tokbase + qy * 128 + qx;
  const int cy = min(max(y, 2), 125), cx = min(max(x, 2), 125);
  const int myryc = cy - rowbase;
  const int rxc   = cx - colbase;
  const int dxpbase = 4 * g - rxc + 2;

  const int rycA = min(max(y0 + 2 * wv,     2), 125) - rowbase;
  const int rycB = min(max(y0 + 2 * wv + 1, 2), 125) - rowbase;
  const int rymin = min(min(rycA, rycB) - 2, 6);

  // ---- Q fragments (already scaled, emb folded) ----
  f16x4 qfrag[4];
#pragma unroll
  for (int h = 0; h < 4; ++h)
    qfrag[h] = *(const f16x4*)&Q[(size_t)tok * CK_ + (hh * 4 + h) * 16 + 4 * g];

  // ---- qe[s][q] = Qs . emb_s via MFMA (A-frags straight from L2) ----
#pragma unroll
  for (int h = 0; h < 4; ++h) {
#pragma unroll
    for (int mt = 0; mt < 2; ++mt) {
      const f16x4 a = *(const f16x4*)&spH[(mt * 16 + l15) * 128 + hh * 64 + h * 16 + 4 * g];
      f32x4 c = {0.f, 0.f, 0.f, 0.f};
      c = mfma16(a, qfrag[h], c);
#pragma unroll
      for (int i = 0; i < 4; ++i) {
        const int s = mt * 16 + 4 * g + i;
        qe_s[h * 2176 + s * 68 + q_glob] = (_Float16)c[i];
      }
    }
  }

  f32x4 o_acc[4];
  float l_acc[4];
#pragma unroll
  for (int h = 0; h < 4; ++h) { o_acc[h] = (f32x4){0.f, 0.f, 0.f, 0.f}; l_acc[h] = 0.f; }

  f16x4 w_frags[4][6];
  const float NEGBIG = -1.0e30f;

  for (int t = 0; t < 3; ++t) {
    __syncthreads();   // qe_s written / prev PV done before overwriting kv_s

    // ---- stage K (frame t): [192 keys][72] f16 (straight f16 copy) ----
    const int kimgbase = (b * 3 + t) * 16384;
    for (int idx = tid; idx < 192 * 16; idx += 256) {
      const int key = idx >> 4, cg = idx & 15;
      const int ny = min(rowbase + (key >> 4), 127);
      const int nx = min(colbase + (key & 15), 127);
      const f16x4 k4 = *(const f16x4*)&K[((size_t)(kimgbase + ny * 128 + nx)) * CK_ + hh * 64 + cg * 4];
      *(f16x4*)&kv_s[key * 72 + cg * 4] = k4;
    }
    __syncthreads();

    // ---- scores: S^T = K . Q^T ; mask+bias+exp2 ; build w fragments ----
#pragma unroll
    for (int h = 0; h < 4; ++h) {
#pragma unroll
      for (int jj = 0; jj < 6; ++jj) {
        const int nt = rymin + jj;
        const f16x4 a = *(const f16x4*)&kv_s[(nt * 16 + l15) * 72 + h * 16 + 4 * g];
        f32x4 c = {0.f, 0.f, 0.f, 0.f};
        c = mfma16(a, qfrag[h], c);
        const int dyp = nt - myryc + 2;
        const bool vy = (unsigned)dyp <= 4u;
        const int s0 = dyp * 5 + dxpbase;
        const int qbase = h * 2176 + q_glob;
        float p0, p1, p2, p3;
#pragma unroll
        for (int i = 0; i < 4; ++i) {
          const int si = min(max(s0 + i, 0), 31);
          const float qv = (float)qe_s[qbase + si * 68];
          float sc = c[i] + qv;
          const bool vi = vy && ((unsigned)(dxpbase + i) <= 4u);
          sc = vi ? sc : NEGBIG;
          const float p = __builtin_amdgcn_exp2f(sc);
          l_acc[h] += p;
          if (i == 0) p0 = p; else if (i == 1) p1 = p; else if (i == 2) p2 = p; else p3 = p;
        }
        f16x4 wf;
        wf[0] = (_Float16)p0; wf[1] = (_Float16)p1;
        wf[2] = (_Float16)p2; wf[3] = (_Float16)p3;
        w_frags[h][jj] = wf;
      }
    }
    __syncthreads();   // all waves done reading K

    // ---- stage V^T (frame t): [64 ch][200] f16 ----
    for (int idx = tid; idx < 192 * 16; idx += 256) {
      const int key = idx >> 4, cg = idx & 15;
      const int ny = min(rowbase + (key >> 4), 127);
      const int nx = min(colbase + (key & 15), 127);
      const f16x4 v4 = *(const f16x4*)&V[((size_t)(kimgbase + ny * 128 + nx)) * CK_ + hh * 64 + cg * 4];
      kv_s[(cg * 4    ) * 200 + key] = v4[0];
      kv_s[(cg * 4 + 1) * 200 + key] = v4[1];
      kv_s[(cg * 4 + 2) * 200 + key] = v4[2];
      kv_s[(cg * 4 + 3) * 200 + key] = v4[3];
    }
    __syncthreads();

    // ---- PV: o^T += V^T . w^T ----
#pragma unroll
    for (int h = 0; h < 4; ++h) {
#pragma unroll
      for (int jj = 0; jj < 6; ++jj) {
        const int nt = rymin + jj;
        const f16x4 a = *(const f16x4*)&kv_s[(h * 16 + l15) * 200 + nt * 16 + 4 * g];
        o_acc[h] = mfma16(a, w_frags[h][jj], o_acc[h]);
      }
    }
  }

  // ---- normalize + store (fp16 ck) ----
#pragma unroll
  for (int h = 0; h < 4; ++h) {
    float lt = l_acc[h];
    lt += __shfl_xor(lt, 16);
    lt += __shfl_xor(lt, 32);
    const float inv = 1.f / lt;
    f16x4 ov;
    ov[0] = (_Float16)(o_acc[h][0] * inv); ov[1] = (_Float16)(o_acc[h][1] * inv);
    ov[2] = (_Float16)(o_acc[h][2] * inv); ov[3] = (_Float16)(o_acc[h][3] * inv);
    *(f16x4*)&ck[(size_t)tok * CK_ + (hh * 4 + h) * 16 + 4 * g] = ov;
  }
}

// ---------------------------------------------------------------------------
// Kernel C: out = ck @ Wo via MFMA (same structure as qkv_mfma, N=128).
// ---------------------------------------------------------------------------
__global__ __launch_bounds__(256) void out_mfma(
    const _Float16* __restrict__ ck, const _Float16* __restrict__ WoT,
    float* __restrict__ out)
{
  __shared__ __align__(16) _Float16 ck_s[64][132];
  const int tid = threadIdx.x;
  const int tok0 = blockIdx.x * 64;

  for (int i = tid; i < 64 * 16; i += 256) {      // i: (token, 8-ch group)
    const int tk = i >> 4, cg = i & 15;
    *(f16x4*)&ck_s[tk][cg * 8] = *(const f16x4*)&ck[(size_t)(tok0 + tk) * C_ + cg * 8];
    *(f16x4*)&ck_s[tk][cg * 8 + 4] = *(const f16x4*)&ck[(size_t)(tok0 + tk) * C_ + cg * 8 + 4];
  }
  __syncthreads();

  const int l = tid & 63, wv = tid >> 6, l15 = l & 15, g = l >> 4;

  f32x4 acc[8];
#pragma unroll
  for (int i = 0; i < 8; ++i) acc[i] = (f32x4){0.f, 0.f, 0.f, 0.f};

  for (int kc = 0; kc < 8; ++kc) {
    const f16x4 bc = *(const f16x4*)&ck_s[wv * 16 + l15][kc * 16 + 4 * g];
    const int ko = kc * 16 + 4 * g;
#pragma unroll
    for (int nt = 0; nt < 8; ++nt) {
      const f16x4 a = *(const f16x4*)&WoT[(nt * 16 + l15) * 128 + ko];
      acc[nt] = mfma16(a, bc, acc[nt]);
    }
  }

  const int tok = tok0 + wv * 16 + l15;
#pragma unroll
  for (int nt = 0; nt < 8; ++nt) {
    float4 ov;
    ov.x = acc[nt][0]; ov.y = acc[nt][1]; ov.z = acc[nt][2]; ov.w = acc[nt][3];
    *(float4*)&out[(size_t)tok * C_ + nt * 16 + 4 * g] = ov;
  }
}

// ---------------------------------------------------------------------------
extern "C" void kernel_launch(void* const* d_in, const int* in_sizes, int n_in,
                              void* d_out, int out_size, void* d_ws, size_t ws_size,
                              hipStream_t stream) {
    const float* values      = (const float*)d_in[0];
    const float* Wq          = (const float*)d_in[1];
    const float* Wk          = (const float*)d_in[2];
    const float* Wv          = (const float*)d_in[3];
    const float* Wo          = (const float*)d_in[4];
    const float* temp_emb    = (const float*)d_in[5];
    const float* spatial_emb = (const float*)d_in[6];
    float* out = (float*)d_out;

    _Float16* Qh  = (_Float16*)d_ws;
    _Float16* Kh  = Qh  + (size_t)NTOK * CK_;
    _Float16* Vh  = Kh  + (size_t)NTOK * CK_;
    _Float16* ckh = Vh  + (size_t)NTOK * CK_;
    _Float16* WqT = ckh + (size_t)NTOK * CK_;
    _Float16* WkT = WqT + 16384;
    _Float16* WvT = WkT + 16384;
    _Float16* WvT2= WvT + 16384;  // WoT
    _Float16* spH = WvT2 + 16384;

    prep<<<272, 256, 0, stream>>>(Wq, Wk, Wv, Wo, spatial_emb,
                                  WqT, WkT, WvT, WvT2, spH);
    qkv_mfma<<<NTOK / 64, 256, 0, stream>>>(values, WqT, WkT, WvT, temp_emb,
                                            spatial_emb, Qh, Kh, Vh);
    attn_mfma<<<3072, 256, 0, stream>>>(Qh, Kh, Vh, spH, ckh);
    out_mfma<<<NTOK / 64, 256, 0, stream>>>(ckh, WvT2, out);
}

// Round 7
// 241.345 us; speedup vs baseline: 4.8348x; 1.8433x over previous
//
#include <hip/hip_runtime.h>
#include <math.h>

// Problem constants (fixed by the reference).
constexpr int B_ = 2, T_ = 3, H_ = 128, W_ = 128, C_ = 128;
constexpr int HEADS_ = 8, D_ = 16, CK_ = 128;
constexpr int RY_ = 2, RX_ = 2, PH_ = 5, PW_ = 5, S_ = 25;
constexpr int NTOK = B_ * T_ * H_ * W_;   // 98304 tokens

typedef float     f32x4 __attribute__((ext_vector_type(4)));
typedef _Float16  f16x4 __attribute__((ext_vector_type(4)));
typedef _Float16  f16x8 __attribute__((ext_vector_type(8)));

static __device__ __forceinline__ f32x4 mfma16(f16x4 a, f16x4 b, f32x4 c) {
#if __has_builtin(__builtin_amdgcn_mfma_f32_16x16x16f16)
  return __builtin_amdgcn_mfma_f32_16x16x16f16(a, b, c, 0, 0, 0);
#else
  asm volatile("v_mfma_f32_16x16x16_f16 %0, %1, %2, %0" : "+v"(c) : "v"(a), "v"(b));
  return c;
#endif
}

// ---------------------------------------------------------------------------
// Kernel P: pack weights fp16 transposed; spatial_emb fp16 padded [32][128];
// tv[t][n] = temp_emb[t] @ Wv (rank-1 correction so V shares the kin input).
// WT = [Wq^T; Wk^T; Wv^T] stacked as [384 n][128 k].
// ---------------------------------------------------------------------------
__global__ __launch_bounds__(256) void prep(
    const float* __restrict__ Wq, const float* __restrict__ Wk,
    const float* __restrict__ Wv, const float* __restrict__ Wo,
    const float* __restrict__ sp, const float* __restrict__ te,
    _Float16* __restrict__ WT, _Float16* __restrict__ WoT,
    _Float16* __restrict__ spH, float* __restrict__ tv)
{
  const int idx = blockIdx.x * 256 + threadIdx.x;
  if (idx < 49152) {
    const int m = idx >> 14, j = idx & 16383, n = j >> 7, k = j & 127;
    const float* Wm = (m == 0) ? Wq : ((m == 1) ? Wk : Wv);
    WT[idx] = (_Float16)Wm[k * 128 + n];
  } else if (idx < 65536) {
    const int j = idx - 49152, n = j >> 7, k = j & 127;
    WoT[j] = (_Float16)Wo[k * 128 + n];
  } else if (idx < 69632) {
    const int j = idx - 65536, s = j >> 7, c = j & 127;
    spH[j] = (s < 25) ? (_Float16)sp[s * 128 + c] : (_Float16)0.f;
  } else if (idx < 70016) {
    const int j = idx - 69632, t = j >> 7, n = j & 127;
    float a = 0.f;
    for (int c = 0; c < 128; ++c) a += te[t * 128 + c] * Wv[c * 128 + n];
    tv[j] = a;
  }
}

// ---------------------------------------------------------------------------
// Kernel A: QKV via MFMA. Block = 128 tokens, 4 waves; wave owns 6 N-tiles
// (of 24 = Q0-7,K0-7,V0-7) x 8 token-tiles -> A-frag (weights) reused 8x.
// Single kin LDS buffer serves all three projections (tv trick for V).
// Q out = (kin@Wq + q_sp_emb) * 0.25*log2e, fp16. K/V out fp16.
// ---------------------------------------------------------------------------
__global__ __launch_bounds__(256, 2) void qkv_mfma(
    const float* __restrict__ values, const _Float16* __restrict__ WT,
    const float* __restrict__ temp_emb, const float* __restrict__ spatial_emb,
    const float* __restrict__ tv,
    _Float16* __restrict__ Qh, _Float16* __restrict__ Kh, _Float16* __restrict__ Vh)
{
  __shared__ __align__(16) _Float16 kin_s[128][132];
  const int tid = threadIdx.x;
  const int tok0 = blockIdx.x * 128;
  const int t = (tok0 >> 14) % T_;

  for (int i = tid; i < 128 * 32; i += 256) {
    const int tk = i >> 5, cg = i & 31;
    const float4 v = *(const float4*)&values[(size_t)(tok0 + tk) * C_ + cg * 4];
    const float4 e = *(const float4*)&temp_emb[t * C_ + cg * 4];
    f16x4 kv;
    kv[0] = (_Float16)(v.x + e.x); kv[1] = (_Float16)(v.y + e.y);
    kv[2] = (_Float16)(v.z + e.z); kv[3] = (_Float16)(v.w + e.w);
    *(f16x4*)&kin_s[tk][cg * 4] = kv;
  }
  __syncthreads();

  const int l = tid & 63, w = tid >> 6, l15 = l & 15, g = l >> 4;

  f32x4 acc[6][8];
#pragma unroll
  for (int j = 0; j < 6; ++j)
#pragma unroll
    for (int tt = 0; tt < 8; ++tt) acc[j][tt] = (f32x4){0.f, 0.f, 0.f, 0.f};

  const _Float16* Wbase = WT + (size_t)(w * 96) * 128;

  for (int kc = 0; kc < 8; ++kc) {
    const int ko = kc * 16 + 4 * g;
    f16x4 bfr[8];
#pragma unroll
    for (int tt = 0; tt < 8; ++tt)
      bfr[tt] = *(const f16x4*)&kin_s[tt * 16 + l15][ko];
#pragma unroll
    for (int j = 0; j < 6; ++j) {
      const f16x4 a = *(const f16x4*)&Wbase[(size_t)(j * 16 + l15) * 128 + ko];
#pragma unroll
      for (int tt = 0; tt < 8; ++tt)
        acc[j][tt] = mfma16(a, bfr[tt], acc[j][tt]);
    }
  }

  constexpr float CSC = 0.25f * 1.44269504088896f;
#pragma unroll
  for (int j = 0; j < 6; ++j) {
    const int ntile = w * 6 + j;
    const int ch0 = (ntile & 7) * 16 + 4 * g;
#pragma unroll
    for (int tt = 0; tt < 8; ++tt) {
      const int tok = tok0 + tt * 16 + l15;
      const size_t o = (size_t)tok * CK_ + ch0;
      f16x4 r;
      if (ntile < 8) {
        const int x = tok & 127, y = (tok >> 7) & 127;
        const int cy = min(max(y, RY_), H_ - 1 - RY_);
        const int cx = min(max(x, RX_), W_ - 1 - RX_);
        const int qsp = (y - cy + RY_) * PW_ + (x - cx + RX_);
        const float4 e = *(const float4*)&spatial_emb[qsp * CK_ + ch0];
        r[0] = (_Float16)((acc[j][tt][0] + e.x) * CSC);
        r[1] = (_Float16)((acc[j][tt][1] + e.y) * CSC);
        r[2] = (_Float16)((acc[j][tt][2] + e.z) * CSC);
        r[3] = (_Float16)((acc[j][tt][3] + e.w) * CSC);
        *(f16x4*)&Qh[o] = r;
      } else if (ntile < 16) {
        r[0] = (_Float16)acc[j][tt][0]; r[1] = (_Float16)acc[j][tt][1];
        r[2] = (_Float16)acc[j][tt][2]; r[3] = (_Float16)acc[j][tt][3];
        *(f16x4*)&Kh[o] = r;
      } else {
        const float4 tve = *(const float4*)&tv[t * 128 + ch0];
        r[0] = (_Float16)(acc[j][tt][0] - tve.x);
        r[1] = (_Float16)(acc[j][tt][1] - tve.y);
        r[2] = (_Float16)(acc[j][tt][2] - tve.z);
        r[3] = (_Float16)(acc[j][tt][3] - tve.w);
        *(f16x4*)&Vh[o] = r;
      }
    }
  }
}

// ---------------------------------------------------------------------------
// Kernel B: MFMA attention v3. Block = (8x8 query tile) x (2-head quarter).
// K and V staged ROW-major [192][44] (b64 coalesced, no transpose). Scores:
// S^T = K.Q^T -> C-frag == A-frag layout of w -> PV is o = w.V with V B-frags
// as 4 stride-44 u16 LDS reads (bank-conflict-free). qe bias table is
// per-wave-private LDS (no barrier); 2 barriers per frame total.
// ---------------------------------------------------------------------------
__global__ __launch_bounds__(256) void attn_mfma(
    const _Float16* __restrict__ Q, const _Float16* __restrict__ K,
    const _Float16* __restrict__ V, const _Float16* __restrict__ spH,
    _Float16* __restrict__ ck)
{
  __shared__ __align__(16) _Float16 K_s[192 * 44];
  __shared__ __align__(16) _Float16 V_s[192 * 44];
  __shared__ __align__(16) _Float16 qe_s[64 * 2 * 36];  // [q][h][s]
  __shared__ float l_s[4][2][16];

  const int tid = threadIdx.x, bid = blockIdx.x;
  const int hq = bid & 3;                 // head quarter: channels hq*32..+31
  const int tile = bid >> 2;
  const int tx = tile & 15, ty = (tile >> 4) & 15, img = tile >> 8;
  const int b = img / 3;
  const int y0 = ty * 8, x0 = tx * 8;
  const int rowbase = max(y0, 2) - 2;
  const int colbase = max(x0, 2) - 2;
  const int tokbase = img * 16384 + y0 * 128 + x0;
  const int chb = hq * 32;

  const int l = tid & 63, wv = tid >> 6, l15 = l & 15, g = l >> 4;
  const int q_glob = wv * 16 + l15;
  const int qy = 2 * wv + (l15 >> 3), qx = l15 & 7;
  const int y = y0 + qy, x = x0 + qx;
  const int tok = tokbase + qy * 128 + qx;
  const int cy = min(max(y, 2), 125), cx = min(max(x, 2), 125);
  const int myryc = cy - rowbase;
  const int rxc = cx - colbase;
  const int dxpbase = 4 * g - rxc + 2;

  const int rycA = min(max(y0 + 2 * wv,     2), 125) - rowbase;
  const int rycB = min(max(y0 + 2 * wv + 1, 2), 125) - rowbase;
  const int rymin = min(min(rycA, rycB) - 2, 6);

  // Q fragments (pre-scaled, spatial emb folded by qkv kernel)
  f16x4 qfrag[2];
#pragma unroll
  for (int h = 0; h < 2; ++h)
    qfrag[h] = *(const f16x4*)&Q[(size_t)tok * CK_ + chb + h * 16 + 4 * g];

  // qe[s][q] = Qs . emb_s via MFMA -> per-wave-private LDS slice (no barrier)
#pragma unroll
  for (int h = 0; h < 2; ++h) {
#pragma unroll
    for (int mt = 0; mt < 2; ++mt) {
      const f16x4 a = *(const f16x4*)&spH[(size_t)(mt * 16 + l15) * 128 + chb + h * 16 + 4 * g];
      f32x4 c = {0.f, 0.f, 0.f, 0.f};
      c = mfma16(a, qfrag[h], c);
      f16x4 q4;
      q4[0] = (_Float16)c[0]; q4[1] = (_Float16)c[1];
      q4[2] = (_Float16)c[2]; q4[3] = (_Float16)c[3];
      *(f16x4*)&qe_s[(q_glob * 2 + h) * 36 + mt * 16 + 4 * g] = q4;
    }
  }

  f32x4 o_acc[2];
  float l_acc[2];
#pragma unroll
  for (int h = 0; h < 2; ++h) { o_acc[h] = (f32x4){0.f, 0.f, 0.f, 0.f}; l_acc[h] = 0.f; }

  for (int t = 0; t < 3; ++t) {
    __syncthreads();   // prev-frame reads done before restaging
    const int kimg = (b * 3 + t) * 16384;
    for (int idx = tid; idx < 1536; idx += 256) {
      const int row = idx >> 3, cg = idx & 7;
      const int ny = min(rowbase + (row >> 4), 127);
      const int nx = colbase + (row & 15);
      const size_t gb = ((size_t)(kimg + ny * 128 + nx)) * CK_ + chb + cg * 4;
      *(f16x4*)&K_s[row * 44 + cg * 4] = *(const f16x4*)&K[gb];
      *(f16x4*)&V_s[row * 44 + cg * 4] = *(const f16x4*)&V[gb];
    }
    __syncthreads();

    f16x4 wfr[2][6];
#pragma unroll
    for (int h = 0; h < 2; ++h) {
#pragma unroll
      for (int jj = 0; jj < 6; ++jj) {
        const int nt = rymin + jj;
        const f16x4 a = *(const f16x4*)&K_s[(nt * 16 + l15) * 44 + h * 16 + 4 * g];
        f32x4 c = {0.f, 0.f, 0.f, 0.f};
        c = mfma16(a, qfrag[h], c);
        const int dyp = nt - myryc + 2;
        const bool vy = (unsigned)dyp <= 4u;
        const int s0 = dyp * 5 + dxpbase;
        const int qbase = (q_glob * 2 + h) * 36;
        float p0, p1, p2, p3;
#pragma unroll
        for (int i = 0; i < 4; ++i) {
          const int si = min(max(s0 + i, 0), 31);
          const float qv = (float)qe_s[qbase + si];
          float sc = c[i] + qv;
          const bool vi = vy && ((unsigned)(dxpbase + i) <= 4u);
          sc = vi ? sc : -1.0e30f;
          const float p = __builtin_amdgcn_exp2f(sc);
          l_acc[h] += p;
          if (i == 0) p0 = p; else if (i == 1) p1 = p; else if (i == 2) p2 = p; else p3 = p;
        }
        f16x4 wf;
        wf[0] = (_Float16)p0; wf[1] = (_Float16)p1;
        wf[2] = (_Float16)p2; wf[3] = (_Float16)p3;
        wfr[h][jj] = wf;
      }
    }

    // PV: o = w . V  (w C-frag reused as A-frag; V row-major B-frags)
#pragma unroll
    for (int h = 0; h < 2; ++h) {
#pragma unroll
      for (int jj = 0; jj < 6; ++jj) {
        const int nt = rymin + jj;
        f16x4 bv;
#pragma unroll
        for (int i = 0; i < 4; ++i)
          bv[i] = V_s[(nt * 16 + 4 * g + i) * 44 + h * 16 + l15];
        o_acc[h] = mfma16(wfr[h][jj], bv, o_acc[h]);
      }
    }
  }

  // normalize: l lives per (q=l15); o lives per (q=4g+i, ch=l15) -> via LDS
#pragma unroll
  for (int h = 0; h < 2; ++h) {
    float lt = l_acc[h];
    lt += __shfl_xor(lt, 16);
    lt += __shfl_xor(lt, 32);
    if (l < 16) l_s[wv][h][l15] = 1.f / lt;
  }
#pragma unroll
  for (int h = 0; h < 2; ++h) {
#pragma unroll
    for (int i = 0; i < 4; ++i) {
      const int q = 4 * g + i;
      const float inv = l_s[wv][h][q];
      const int qtok = tokbase + (2 * wv + (q >> 3)) * 128 + (q & 7);
      ck[(size_t)qtok * CK_ + chb + h * 16 + l15] = (_Float16)(o_acc[h][i] * inv);
    }
  }
}

// ---------------------------------------------------------------------------
// Kernel C: out = ck @ Wo via MFMA. Block = 128 tokens; wave = 2 N-tiles x 8
// token-tiles. fp32 output.
// ---------------------------------------------------------------------------
__global__ __launch_bounds__(256) void out_mfma(
    const _Float16* __restrict__ ck, const _Float16* __restrict__ WoT,
    float* __restrict__ out)
{
  __shared__ __align__(16) _Float16 ck_s[128][136];
  const int tid = threadIdx.x;
  const int tok0 = blockIdx.x * 128;

  for (int i = tid; i < 128 * 16; i += 256) {
    const int tk = i >> 4, cg = i & 15;
    *(f16x8*)&ck_s[tk][cg * 8] = *(const f16x8*)&ck[(size_t)(tok0 + tk) * C_ + cg * 8];
  }
  __syncthreads();

  const int l = tid & 63, w = tid >> 6, l15 = l & 15, g = l >> 4;

  f32x4 acc[2][8];
#pragma unroll
  for (int j = 0; j < 2; ++j)
#pragma unroll
    for (int tt = 0; tt < 8; ++tt) acc[j][tt] = (f32x4){0.f, 0.f, 0.f, 0.f};

  for (int kc = 0; kc < 8; ++kc) {
    const int ko = kc * 16 + 4 * g;
    f16x4 bfr[8];
#pragma unroll
    for (int tt = 0; tt < 8; ++tt)
      bfr[tt] = *(const f16x4*)&ck_s[tt * 16 + l15][ko];
#pragma unroll
    for (int j = 0; j < 2; ++j) {
      const f16x4 a = *(const f16x4*)&WoT[(size_t)((w * 2 + j) * 16 + l15) * 128 + ko];
#pragma unroll
      for (int tt = 0; tt < 8; ++tt)
        acc[j][tt] = mfma16(a, bfr[tt], acc[j][tt]);
    }
  }

#pragma unroll
  for (int j = 0; j < 2; ++j) {
    const int ch0 = (w * 2 + j) * 16 + 4 * g;
#pragma unroll
    for (int tt = 0; tt < 8; ++tt) {
      const int tok = tok0 + tt * 16 + l15;
      float4 ov;
      ov.x = acc[j][tt][0]; ov.y = acc[j][tt][1];
      ov.z = acc[j][tt][2]; ov.w = acc[j][tt][3];
      *(float4*)&out[(size_t)tok * C_ + ch0] = ov;
    }
  }
}

// ---------------------------------------------------------------------------
extern "C" void kernel_launch(void* const* d_in, const int* in_sizes, int n_in,
                              void* d_out, int out_size, void* d_ws, size_t ws_size,
                              hipStream_t stream) {
    const float* values      = (const float*)d_in[0];
    const float* Wq          = (const float*)d_in[1];
    const float* Wk          = (const float*)d_in[2];
    const float* Wv          = (const float*)d_in[3];
    const float* Wo          = (const float*)d_in[4];
    const float* temp_emb    = (const float*)d_in[5];
    const float* spatial_emb = (const float*)d_in[6];
    float* out = (float*)d_out;

    const size_t NC = (size_t)NTOK * CK_;
    _Float16* Qh  = (_Float16*)d_ws;
    _Float16* Kh  = Qh  + NC;
    _Float16* Vh  = Kh  + NC;
    _Float16* ckh = Vh  + NC;
    _Float16* WT  = ckh + NC;          // [384][128]
    _Float16* WoT = WT  + 49152;       // [128][128]
    _Float16* spH = WoT + 16384;       // [32][128]
    float*    tv  = (float*)(spH + 4096);  // [3][128]

    prep<<<274, 256, 0, stream>>>(Wq, Wk, Wv, Wo, spatial_emb, temp_emb,
                                  WT, WoT, spH, tv);
    qkv_mfma<<<NTOK / 128, 256, 0, stream>>>(values, WT, temp_emb, spatial_emb,
                                             tv, Qh, Kh, Vh);
    attn_mfma<<<6144, 256, 0, stream>>>(Qh, Kh, Vh, spH, ckh);
    out_mfma<<<NTOK / 128, 256, 0, stream>>>(ckh, WoT, out);
}

// Round 9
// 234.505 us; speedup vs baseline: 4.9758x; 1.0292x over previous
//
#include <hip/hip_runtime.h>
#include <math.h>

// Problem constants (fixed by the reference).
constexpr int B_ = 2, T_ = 3, H_ = 128, W_ = 128, C_ = 128;
constexpr int HEADS_ = 8, D_ = 16, CK_ = 128;
constexpr int RY_ = 2, RX_ = 2, PH_ = 5, PW_ = 5, S_ = 25;
constexpr int NTOK = B_ * T_ * H_ * W_;   // 98304 tokens

typedef float     f32x4 __attribute__((ext_vector_type(4)));
typedef _Float16  f16x4 __attribute__((ext_vector_type(4)));
typedef _Float16  f16x8 __attribute__((ext_vector_type(8)));

static __device__ __forceinline__ f32x4 mfma16(f16x4 a, f16x4 b, f32x4 c) {
#if __has_builtin(__builtin_amdgcn_mfma_f32_16x16x16f16)
  return __builtin_amdgcn_mfma_f32_16x16x16f16(a, b, c, 0, 0, 0);
#else
  asm volatile("v_mfma_f32_16x16x16_f16 %0, %1, %2, %0" : "+v"(c) : "v"(a), "v"(b));
  return c;
#endif
}

// ---------------------------------------------------------------------------
// Kernel P: pack weights fp16 transposed; spatial_emb fp16 padded [32][128];
// tv[t][n] = temp_emb[t] @ Wv (rank-1 correction so V shares the kin input).
// WT = [Wq^T; Wk^T; Wv^T] stacked as [384 n][128 k].
// ---------------------------------------------------------------------------
__global__ __launch_bounds__(256) void prep(
    const float* __restrict__ Wq, const float* __restrict__ Wk,
    const float* __restrict__ Wv, const float* __restrict__ Wo,
    const float* __restrict__ sp, const float* __restrict__ te,
    _Float16* __restrict__ WT, _Float16* __restrict__ WoT,
    _Float16* __restrict__ spH, float* __restrict__ tv)
{
  const int idx = blockIdx.x * 256 + threadIdx.x;
  if (idx < 49152) {
    const int m = idx >> 14, j = idx & 16383, n = j >> 7, k = j & 127;
    const float* Wm = (m == 0) ? Wq : ((m == 1) ? Wk : Wv);
    WT[idx] = (_Float16)Wm[k * 128 + n];
  } else if (idx < 65536) {
    const int j = idx - 49152, n = j >> 7, k = j & 127;
    WoT[j] = (_Float16)Wo[k * 128 + n];
  } else if (idx < 69632) {
    const int j = idx - 65536, s = j >> 7, c = j & 127;
    spH[j] = (s < 25) ? (_Float16)sp[s * 128 + c] : (_Float16)0.f;
  } else if (idx < 70016) {
    const int j = idx - 69632, t = j >> 7, n = j & 127;
    float a = 0.f;
    for (int c = 0; c < 128; ++c) a += te[t * 128 + c] * Wv[c * 128 + n];
    tv[j] = a;
  }
}

// ---------------------------------------------------------------------------
// Kernel A: QKV via MFMA. Block = 128 tokens, 4 waves; wave owns 6 N-tiles
// (of 24 = Q0-7,K0-7,V0-7) x 8 token-tiles -> A-frag (weights) reused 8x.
// kin_s stride 140: bank0 = (6r + 2g) near-uniform.
// ---------------------------------------------------------------------------
__global__ __launch_bounds__(256, 2) void qkv_mfma(
    const float* __restrict__ values, const _Float16* __restrict__ WT,
    const float* __restrict__ temp_emb, const float* __restrict__ spatial_emb,
    const float* __restrict__ tv,
    _Float16* __restrict__ Qh, _Float16* __restrict__ Kh, _Float16* __restrict__ Vh)
{
  __shared__ __align__(16) _Float16 kin_s[128][140];
  const int tid = threadIdx.x;
  const int tok0 = blockIdx.x * 128;
  const int t = (tok0 >> 14) % T_;

  for (int i = tid; i < 128 * 32; i += 256) {
    const int tk = i >> 5, cg = i & 31;
    const float4 v = *(const float4*)&values[(size_t)(tok0 + tk) * C_ + cg * 4];
    const float4 e = *(const float4*)&temp_emb[t * C_ + cg * 4];
    f16x4 kv;
    kv[0] = (_Float16)(v.x + e.x); kv[1] = (_Float16)(v.y + e.y);
    kv[2] = (_Float16)(v.z + e.z); kv[3] = (_Float16)(v.w + e.w);
    *(f16x4*)&kin_s[tk][cg * 4] = kv;
  }
  __syncthreads();

  const int l = tid & 63, w = tid >> 6, l15 = l & 15, g = l >> 4;

  f32x4 acc[6][8];
#pragma unroll
  for (int j = 0; j < 6; ++j)
#pragma unroll
    for (int tt = 0; tt < 8; ++tt) acc[j][tt] = (f32x4){0.f, 0.f, 0.f, 0.f};

  const _Float16* Wbase = WT + (size_t)(w * 96) * 128;

  for (int kc = 0; kc < 8; ++kc) {
    const int ko = kc * 16 + 4 * g;
    f16x4 bfr[8];
#pragma unroll
    for (int tt = 0; tt < 8; ++tt)
      bfr[tt] = *(const f16x4*)&kin_s[tt * 16 + l15][ko];
#pragma unroll
    for (int j = 0; j < 6; ++j) {
      const f16x4 a = *(const f16x4*)&Wbase[(size_t)(j * 16 + l15) * 128 + ko];
#pragma unroll
      for (int tt = 0; tt < 8; ++tt)
        acc[j][tt] = mfma16(a, bfr[tt], acc[j][tt]);
    }
  }

  constexpr float CSC = 0.25f * 1.44269504088896f;
#pragma unroll
  for (int j = 0; j < 6; ++j) {
    const int ntile = w * 6 + j;
    const int ch0 = (ntile & 7) * 16 + 4 * g;
#pragma unroll
    for (int tt = 0; tt < 8; ++tt) {
      const int tok = tok0 + tt * 16 + l15;
      const size_t o = (size_t)tok * CK_ + ch0;
      f16x4 r;
      if (ntile < 8) {
        const int x = tok & 127, y = (tok >> 7) & 127;
        const int cy = min(max(y, RY_), H_ - 1 - RY_);
        const int cx = min(max(x, RX_), W_ - 1 - RX_);
        const int qsp = (y - cy + RY_) * PW_ + (x - cx + RX_);
        const float4 e = *(const float4*)&spatial_emb[qsp * CK_ + ch0];
        r[0] = (_Float16)((acc[j][tt][0] + e.x) * CSC);
        r[1] = (_Float16)((acc[j][tt][1] + e.y) * CSC);
        r[2] = (_Float16)((acc[j][tt][2] + e.z) * CSC);
        r[3] = (_Float16)((acc[j][tt][3] + e.w) * CSC);
        *(f16x4*)&Qh[o] = r;
      } else if (ntile < 16) {
        r[0] = (_Float16)acc[j][tt][0]; r[1] = (_Float16)acc[j][tt][1];
        r[2] = (_Float16)acc[j][tt][2]; r[3] = (_Float16)acc[j][tt][3];
        *(f16x4*)&Kh[o] = r;
      } else {
        const float4 tve = *(const float4*)&tv[t * 128 + ch0];
        r[0] = (_Float16)(acc[j][tt][0] - tve.x);
        r[1] = (_Float16)(acc[j][tt][1] - tve.y);
        r[2] = (_Float16)(acc[j][tt][2] - tve.z);
        r[3] = (_Float16)(acc[j][tt][3] - tve.w);
        *(f16x4*)&Vh[o] = r;
      }
    }
  }
}

// ---------------------------------------------------------------------------
// Kernel B: MFMA attention v4. v3 + (a) XCD-aware BIJECTIVE block swizzle
// (bid0 = 8a+b -> b*768 + a; ADD not OR — R8's OR had overlapping bit ranges
// and was non-bijective); (b) T14 async staging: addresses hoisted, next
// frame's K/V prefetched into 24 VGPRs one compute-phase early, regs->LDS
// after the barrier; 5 barriers total, load latency hidden under score+PV.
// ---------------------------------------------------------------------------
__global__ __launch_bounds__(256) void attn_mfma(
    const _Float16* __restrict__ Q, const _Float16* __restrict__ K,
    const _Float16* __restrict__ V, const _Float16* __restrict__ spH,
    _Float16* __restrict__ ck)
{
  __shared__ __align__(16) _Float16 K_s[192 * 44];
  __shared__ __align__(16) _Float16 V_s[192 * 44];
  __shared__ __align__(16) _Float16 qe_s[64 * 2 * 36];  // [q][h][s]
  __shared__ float l_s[4][2][16];

  const int tid = threadIdx.x;
  const int bid0 = blockIdx.x;
  const int bid = (bid0 & 7) * 768 + (bid0 >> 3);   // 6144 = 8 XCD x 768
  const int hq = bid & 3;                 // head quarter: channels hq*32..+31
  const int tile = bid >> 2;
  const int tx = tile & 15, ty = (tile >> 4) & 15, img = tile >> 8;
  const int b = img / 3;
  const int y0 = ty * 8, x0 = tx * 8;
  const int rowbase = max(y0, 2) - 2;
  const int colbase = max(x0, 2) - 2;
  const int tokbase = img * 16384 + y0 * 128 + x0;
  const int chb = hq * 32;

  const int l = tid & 63, wv = tid >> 6, l15 = l & 15, g = l >> 4;
  const int q_glob = wv * 16 + l15;
  const int qy = 2 * wv + (l15 >> 3), qx = l15 & 7;
  const int y = y0 + qy, x = x0 + qx;
  const int tok = tokbase + qy * 128 + qx;
  const int cy = min(max(y, 2), 125), cx = min(max(x, 2), 125);
  const int myryc = cy - rowbase;
  const int rxc = cx - colbase;
  const int dxpbase = 4 * g - rxc + 2;

  const int rycA = min(max(y0 + 2 * wv,     2), 125) - rowbase;
  const int rycB = min(max(y0 + 2 * wv + 1, 2), 125) - rowbase;
  const int rymin = min(min(rycA, rycB) - 2, 6);

  // ---- hoisted staging offsets (fixed across frames) ----
  int poff[6], ldoff[6];
#pragma unroll
  for (int it = 0; it < 6; ++it) {
    const int idx = tid + it * 256;
    const int row = idx >> 3, cg = idx & 7;
    const int ny = min(rowbase + (row >> 4), 127);
    const int nx = min(colbase + (row & 15), 127);
    poff[it] = (ny * 128 + nx) * CK_ + chb + cg * 4;
    ldoff[it] = row * 44 + cg * 4;
  }
  const size_t imgstep = (size_t)16384 * CK_;
  const _Float16* Kp = K + (size_t)(b * 3) * imgstep;
  const _Float16* Vp = V + (size_t)(b * 3) * imgstep;

  // ---- prefetch frame 0 (in flight during qfrag/qe setup) ----
  f16x4 kpre[6], vpre[6];
#pragma unroll
  for (int it = 0; it < 6; ++it) {
    kpre[it] = *(const f16x4*)&Kp[poff[it]];
    vpre[it] = *(const f16x4*)&Vp[poff[it]];
  }

  // Q fragments (pre-scaled, spatial emb folded by qkv kernel)
  f16x4 qfrag[2];
#pragma unroll
  for (int h = 0; h < 2; ++h)
    qfrag[h] = *(const f16x4*)&Q[(size_t)tok * CK_ + chb + h * 16 + 4 * g];

  // qe[s][q] = Qs . emb_s via MFMA -> per-wave-private LDS slice (no barrier)
#pragma unroll
  for (int h = 0; h < 2; ++h) {
#pragma unroll
    for (int mt = 0; mt < 2; ++mt) {
      const f16x4 a = *(const f16x4*)&spH[(size_t)(mt * 16 + l15) * 128 + chb + h * 16 + 4 * g];
      f32x4 c = {0.f, 0.f, 0.f, 0.f};
      c = mfma16(a, qfrag[h], c);
      f16x4 q4;
      q4[0] = (_Float16)c[0]; q4[1] = (_Float16)c[1];
      q4[2] = (_Float16)c[2]; q4[3] = (_Float16)c[3];
      *(f16x4*)&qe_s[(q_glob * 2 + h) * 36 + mt * 16 + 4 * g] = q4;
    }
  }

  f32x4 o_acc[2];
  float l_acc[2];
#pragma unroll
  for (int h = 0; h < 2; ++h) { o_acc[h] = (f32x4){0.f, 0.f, 0.f, 0.f}; l_acc[h] = 0.f; }

#pragma unroll
  for (int t = 0; t < 3; ++t) {
    if (t) __syncthreads();           // prev-frame reads done before restage
    // regs -> LDS (prefetched)
#pragma unroll
    for (int it = 0; it < 6; ++it) {
      *(f16x4*)&K_s[ldoff[it]] = kpre[it];
      *(f16x4*)&V_s[ldoff[it]] = vpre[it];
    }
    __syncthreads();                  // staging visible
    // issue next frame's loads BEFORE compute -> latency hidden
    if (t < 2) {
      const _Float16* Kt = Kp + (size_t)(t + 1) * imgstep;
      const _Float16* Vt = Vp + (size_t)(t + 1) * imgstep;
#pragma unroll
      for (int it = 0; it < 6; ++it) {
        kpre[it] = *(const f16x4*)&Kt[poff[it]];
        vpre[it] = *(const f16x4*)&Vt[poff[it]];
      }
    }

    f16x4 wfr[2][6];
#pragma unroll
    for (int h = 0; h < 2; ++h) {
#pragma unroll
      for (int jj = 0; jj < 6; ++jj) {
        const int nt = rymin + jj;
        const f16x4 a = *(const f16x4*)&K_s[(nt * 16 + l15) * 44 + h * 16 + 4 * g];
        f32x4 c = {0.f, 0.f, 0.f, 0.f};
        c = mfma16(a, qfrag[h], c);
        const int dyp = nt - myryc + 2;
        const bool vy = (unsigned)dyp <= 4u;
        const int s0 = dyp * 5 + dxpbase;
        const int qbase = (q_glob * 2 + h) * 36;
        float p0, p1, p2, p3;
#pragma unroll
        for (int i = 0; i < 4; ++i) {
          const int si = min(max(s0 + i, 0), 31);
          const float qv = (float)qe_s[qbase + si];
          float sc = c[i] + qv;
          const bool vi = vy && ((unsigned)(dxpbase + i) <= 4u);
          sc = vi ? sc : -1.0e30f;
          const float p = __builtin_amdgcn_exp2f(sc);
          l_acc[h] += p;
          if (i == 0) p0 = p; else if (i == 1) p1 = p; else if (i == 2) p2 = p; else p3 = p;
        }
        f16x4 wf;
        wf[0] = (_Float16)p0; wf[1] = (_Float16)p1;
        wf[2] = (_Float16)p2; wf[3] = (_Float16)p3;
        wfr[h][jj] = wf;
      }
    }

    // PV: o = w . V  (w C-frag reused as A-frag; V row-major B-frags)
#pragma unroll
    for (int h = 0; h < 2; ++h) {
#pragma unroll
      for (int jj = 0; jj < 6; ++jj) {
        const int nt = rymin + jj;
        f16x4 bv;
#pragma unroll
        for (int i = 0; i < 4; ++i)
          bv[i] = V_s[(nt * 16 + 4 * g + i) * 44 + h * 16 + l15];
        o_acc[h] = mfma16(wfr[h][jj], bv, o_acc[h]);
      }
    }
  }

  // normalize: l lives per (q=l15); o lives per (q=4g+i, ch=l15) -> via LDS
#pragma unroll
  for (int h = 0; h < 2; ++h) {
    float lt = l_acc[h];
    lt += __shfl_xor(lt, 16);
    lt += __shfl_xor(lt, 32);
    if (l < 16) l_s[wv][h][l15] = 1.f / lt;
  }
#pragma unroll
  for (int h = 0; h < 2; ++h) {
#pragma unroll
    for (int i = 0; i < 4; ++i) {
      const int q = 4 * g + i;
      const float inv = l_s[wv][h][q];
      const int qtok = tokbase + (2 * wv + (q >> 3)) * 128 + (q & 7);
      ck[(size_t)qtok * CK_ + chb + h * 16 + l15] = (_Float16)(o_acc[h][i] * inv);
    }
  }
}

// ---------------------------------------------------------------------------
// Kernel C: out = ck @ Wo via MFMA. Block = 128 tokens; wave = 2 N-tiles x 8
// token-tiles. ck_s stride 152 (16B-aligned rows, bank spread ~2/bank).
// ---------------------------------------------------------------------------
__global__ __launch_bounds__(256) void out_mfma(
    const _Float16* __restrict__ ck, const _Float16* __restrict__ WoT,
    float* __restrict__ out)
{
  __shared__ __align__(16) _Float16 ck_s[128][152];
  const int tid = threadIdx.x;
  const int tok0 = blockIdx.x * 128;

  for (int i = tid; i < 128 * 16; i += 256) {
    const int tk = i >> 4, cg = i & 15;
    *(f16x8*)&ck_s[tk][cg * 8] = *(const f16x8*)&ck[(size_t)(tok0 + tk) * C_ + cg * 8];
  }
  __syncthreads();

  const int l = tid & 63, w = tid >> 6, l15 = l & 15, g = l >> 4;

  f32x4 acc[2][8];
#pragma unroll
  for (int j = 0; j < 2; ++j)
#pragma unroll
    for (int tt = 0; tt < 8; ++tt) acc[j][tt] = (f32x4){0.f, 0.f, 0.f, 0.f};

  for (int kc = 0; kc < 8; ++kc) {
    const int ko = kc * 16 + 4 * g;
    f16x4 bfr[8];
#pragma unroll
    for (int tt = 0; tt < 8; ++tt)
      bfr[tt] = *(const f16x4*)&ck_s[tt * 16 + l15][ko];
#pragma unroll
    for (int j = 0; j < 2; ++j) {
      const f16x4 a = *(const f16x4*)&WoT[(size_t)((w * 2 + j) * 16 + l15) * 128 + ko];
#pragma unroll
      for (int tt = 0; tt < 8; ++tt)
        acc[j][tt] = mfma16(a, bfr[tt], acc[j][tt]);
    }
  }

#pragma unroll
  for (int j = 0; j < 2; ++j) {
    const int ch0 = (w * 2 + j) * 16 + 4 * g;
#pragma unroll
    for (int tt = 0; tt < 8; ++tt) {
      const int tok = tok0 + tt * 16 + l15;
      float4 ov;
      ov.x = acc[j][tt][0]; ov.y = acc[j][tt][1];
      ov.z = acc[j][tt][2]; ov.w = acc[j][tt][3];
      *(float4*)&out[(size_t)tok * C_ + ch0] = ov;
    }
  }
}

// ---------------------------------------------------------------------------
extern "C" void kernel_launch(void* const* d_in, const int* in_sizes, int n_in,
                              void* d_out, int out_size, void* d_ws, size_t ws_size,
                              hipStream_t stream) {
    const float* values      = (const float*)d_in[0];
    const float* Wq          = (const float*)d_in[1];
    const float* Wk          = (const float*)d_in[2];
    const float* Wv          = (const float*)d_in[3];
    const float* Wo          = (const float*)d_in[4];
    const float* temp_emb    = (const float*)d_in[5];
    const float* spatial_emb = (const float*)d_in[6];
    float* out = (float*)d_out;

    const size_t NC = (size_t)NTOK * CK_;
    _Float16* Qh  = (_Float16*)d_ws;
    _Float16* Kh  = Qh  + NC;
    _Float16* Vh  = Kh  + NC;
    _Float16* ckh = Vh  + NC;
    _Float16* WT  = ckh + NC;          // [384][128]
    _Float16* WoT = WT  + 49152;       // [128][128]
    _Float16* spH = WoT + 16384;       // [32][128]
    float*    tv  = (float*)(spH + 4096);  // [3][128]

    prep<<<274, 256, 0, stream>>>(Wq, Wk, Wv, Wo, spatial_emb, temp_emb,
                                  WT, WoT, spH, tv);
    qkv_mfma<<<NTOK / 128, 256, 0, stream>>>(values, WT, temp_emb, spatial_emb,
                                             tv, Qh, Kh, Vh);
    attn_mfma<<<6144, 256, 0, stream>>>(Qh, Kh, Vh, spH, ckh);
    out_mfma<<<NTOK / 128, 256, 0, stream>>>(ckh, WoT, out);
}

// Round 10
// 181.193 us; speedup vs baseline: 6.4399x; 1.2942x over previous
//
#include <hip/hip_runtime.h>
#include <math.h>

// Problem constants (fixed by the reference).
constexpr int B_ = 2, T_ = 3, H_ = 128, W_ = 128, C_ = 128;
constexpr int HEADS_ = 8, D_ = 16, CK_ = 128;
constexpr int RY_ = 2, RX_ = 2, PH_ = 5, PW_ = 5, S_ = 25;
constexpr int NTOK = B_ * T_ * H_ * W_;   // 98304 tokens

typedef float     f32x4 __attribute__((ext_vector_type(4)));
typedef _Float16  f16x4 __attribute__((ext_vector_type(4)));
typedef _Float16  f16x8 __attribute__((ext_vector_type(8)));

static __device__ __forceinline__ f32x4 mfma16(f16x4 a, f16x4 b, f32x4 c) {
#if __has_builtin(__builtin_amdgcn_mfma_f32_16x16x16f16)
  return __builtin_amdgcn_mfma_f32_16x16x16f16(a, b, c, 0, 0, 0);
#else
  asm volatile("v_mfma_f32_16x16x16_f16 %0, %1, %2, %0" : "+v"(c) : "v"(a), "v"(b));
  return c;
#endif
}

// ---------------------------------------------------------------------------
// Kernel P: pack weights fp16 transposed; spatial_emb fp16 padded [32][128];
// tv[t][n] = temp_emb[t] @ Wv (rank-1 correction so V shares the kin input).
// WT = [Wq^T; Wk^T; Wv^T] stacked as [384 n][128 k].
// ---------------------------------------------------------------------------
__global__ __launch_bounds__(256) void prep(
    const float* __restrict__ Wq, const float* __restrict__ Wk,
    const float* __restrict__ Wv, const float* __restrict__ Wo,
    const float* __restrict__ sp, const float* __restrict__ te,
    _Float16* __restrict__ WT, _Float16* __restrict__ WoT,
    _Float16* __restrict__ spH, float* __restrict__ tv)
{
  const int idx = blockIdx.x * 256 + threadIdx.x;
  if (idx < 49152) {
    const int m = idx >> 14, j = idx & 16383, n = j >> 7, k = j & 127;
    const float* Wm = (m == 0) ? Wq : ((m == 1) ? Wk : Wv);
    WT[idx] = (_Float16)Wm[k * 128 + n];
  } else if (idx < 65536) {
    const int j = idx - 49152, n = j >> 7, k = j & 127;
    WoT[j] = (_Float16)Wo[k * 128 + n];
  } else if (idx < 69632) {
    const int j = idx - 65536, s = j >> 7, c = j & 127;
    spH[j] = (s < 25) ? (_Float16)sp[s * 128 + c] : (_Float16)0.f;
  } else if (idx < 70016) {
    const int j = idx - 69632, t = j >> 7, n = j & 127;
    float a = 0.f;
    for (int c = 0; c < 128; ++c) a += te[t * 128 + c] * Wv[c * 128 + n];
    tv[j] = a;
  }
}

// ---------------------------------------------------------------------------
// Kernel A: QKV via MFMA, occupancy-fixed. Block = 64 tokens, 4 waves; wave
// owns 6 N-tiles x 4 token-tiles -> acc = 24 f32x4 = 96 VGPRs (R9's 48 acc
// = 192 regs forced 1 wave/SIMD and made the kernel latency-bound at 117us).
// launch_bounds(256,3): VGPR cap 170, 3 waves/SIMD. kc loop unrolled so the
// compiler pipelines the 48 A-frag L2 loads. kin_s stride 140 (0 conflicts,
// verified R9).
// ---------------------------------------------------------------------------
__global__ __launch_bounds__(256, 3) void qkv_mfma(
    const float* __restrict__ values, const _Float16* __restrict__ WT,
    const float* __restrict__ temp_emb, const float* __restrict__ spatial_emb,
    const float* __restrict__ tv,
    _Float16* __restrict__ Qh, _Float16* __restrict__ Kh, _Float16* __restrict__ Vh)
{
  __shared__ __align__(16) _Float16 kin_s[64][140];
  const int tid = threadIdx.x;
  const int tok0 = blockIdx.x * 64;
  const int t = (tok0 >> 14) % T_;

  for (int i = tid; i < 64 * 32; i += 256) {
    const int tk = i >> 5, cg = i & 31;
    const float4 v = *(const float4*)&values[(size_t)(tok0 + tk) * C_ + cg * 4];
    const float4 e = *(const float4*)&temp_emb[t * C_ + cg * 4];
    f16x4 kv;
    kv[0] = (_Float16)(v.x + e.x); kv[1] = (_Float16)(v.y + e.y);
    kv[2] = (_Float16)(v.z + e.z); kv[3] = (_Float16)(v.w + e.w);
    *(f16x4*)&kin_s[tk][cg * 4] = kv;
  }
  __syncthreads();

  const int l = tid & 63, w = tid >> 6, l15 = l & 15, g = l >> 4;

  f32x4 acc[6][4];
#pragma unroll
  for (int j = 0; j < 6; ++j)
#pragma unroll
    for (int tt = 0; tt < 4; ++tt) acc[j][tt] = (f32x4){0.f, 0.f, 0.f, 0.f};

  const _Float16* Wbase = WT + (size_t)(w * 96) * 128;

#pragma unroll
  for (int kc = 0; kc < 8; ++kc) {
    const int ko = kc * 16 + 4 * g;
    f16x4 bfr[4];
#pragma unroll
    for (int tt = 0; tt < 4; ++tt)
      bfr[tt] = *(const f16x4*)&kin_s[tt * 16 + l15][ko];
#pragma unroll
    for (int j = 0; j < 6; ++j) {
      const f16x4 a = *(const f16x4*)&Wbase[(size_t)(j * 16 + l15) * 128 + ko];
#pragma unroll
      for (int tt = 0; tt < 4; ++tt)
        acc[j][tt] = mfma16(a, bfr[tt], acc[j][tt]);
    }
  }

  constexpr float CSC = 0.25f * 1.44269504088896f;
#pragma unroll
  for (int j = 0; j < 6; ++j) {
    const int ntile = w * 6 + j;
    const int ch0 = (ntile & 7) * 16 + 4 * g;
#pragma unroll
    for (int tt = 0; tt < 4; ++tt) {
      const int tok = tok0 + tt * 16 + l15;
      const size_t o = (size_t)tok * CK_ + ch0;
      f16x4 r;
      if (ntile < 8) {
        const int x = tok & 127, y = (tok >> 7) & 127;
        const int cy = min(max(y, RY_), H_ - 1 - RY_);
        const int cx = min(max(x, RX_), W_ - 1 - RX_);
        const int qsp = (y - cy + RY_) * PW_ + (x - cx + RX_);
        const float4 e = *(const float4*)&spatial_emb[qsp * CK_ + ch0];
        r[0] = (_Float16)((acc[j][tt][0] + e.x) * CSC);
        r[1] = (_Float16)((acc[j][tt][1] + e.y) * CSC);
        r[2] = (_Float16)((acc[j][tt][2] + e.z) * CSC);
        r[3] = (_Float16)((acc[j][tt][3] + e.w) * CSC);
        *(f16x4*)&Qh[o] = r;
      } else if (ntile < 16) {
        r[0] = (_Float16)acc[j][tt][0]; r[1] = (_Float16)acc[j][tt][1];
        r[2] = (_Float16)acc[j][tt][2]; r[3] = (_Float16)acc[j][tt][3];
        *(f16x4*)&Kh[o] = r;
      } else {
        const float4 tve = *(const float4*)&tv[t * 128 + ch0];
        r[0] = (_Float16)(acc[j][tt][0] - tve.x);
        r[1] = (_Float16)(acc[j][tt][1] - tve.y);
        r[2] = (_Float16)(acc[j][tt][2] - tve.z);
        r[3] = (_Float16)(acc[j][tt][3] - tve.w);
        *(f16x4*)&Vh[o] = r;
      }
    }
  }
}

// ---------------------------------------------------------------------------
// Kernel B: MFMA attention v5. = v4 (bijective XCD swizzle + async reg
// prefetch) + qe table shrunk 36->28 entries (si clamped to 24; rows 25..27
// hold garbage but are only read masked) + s_setprio(1) around score+PV.
// ---------------------------------------------------------------------------
__global__ __launch_bounds__(256) void attn_mfma(
    const _Float16* __restrict__ Q, const _Float16* __restrict__ K,
    const _Float16* __restrict__ V, const _Float16* __restrict__ spH,
    _Float16* __restrict__ ck)
{
  __shared__ __align__(16) _Float16 K_s[192 * 44];
  __shared__ __align__(16) _Float16 V_s[192 * 44];
  __shared__ __align__(16) _Float16 qe_s[64 * 2 * 28];  // [q][h][s<28]
  __shared__ float l_s[4][2][16];

  const int tid = threadIdx.x;
  const int bid0 = blockIdx.x;
  const int bid = (bid0 & 7) * 768 + (bid0 >> 3);   // bijective: 8a+b -> 768b+a
  const int hq = bid & 3;                 // head quarter: channels hq*32..+31
  const int tile = bid >> 2;
  const int tx = tile & 15, ty = (tile >> 4) & 15, img = tile >> 8;
  const int b = img / 3;
  const int y0 = ty * 8, x0 = tx * 8;
  const int rowbase = max(y0, 2) - 2;
  const int colbase = max(x0, 2) - 2;
  const int tokbase = img * 16384 + y0 * 128 + x0;
  const int chb = hq * 32;

  const int l = tid & 63, wv = tid >> 6, l15 = l & 15, g = l >> 4;
  const int q_glob = wv * 16 + l15;
  const int qy = 2 * wv + (l15 >> 3), qx = l15 & 7;
  const int y = y0 + qy, x = x0 + qx;
  const int tok = tokbase + qy * 128 + qx;
  const int cy = min(max(y, 2), 125), cx = min(max(x, 2), 125);
  const int myryc = cy - rowbase;
  const int rxc = cx - colbase;
  const int dxpbase = 4 * g - rxc + 2;

  const int rycA = min(max(y0 + 2 * wv,     2), 125) - rowbase;
  const int rycB = min(max(y0 + 2 * wv + 1, 2), 125) - rowbase;
  const int rymin = min(min(rycA, rycB) - 2, 6);

  // ---- hoisted staging offsets (fixed across frames) ----
  int poff[6], ldoff[6];
#pragma unroll
  for (int it = 0; it < 6; ++it) {
    const int idx = tid + it * 256;
    const int row = idx >> 3, cg = idx & 7;
    const int ny = min(rowbase + (row >> 4), 127);
    const int nx = min(colbase + (row & 15), 127);
    poff[it] = (ny * 128 + nx) * CK_ + chb + cg * 4;
    ldoff[it] = row * 44 + cg * 4;
  }
  const size_t imgstep = (size_t)16384 * CK_;
  const _Float16* Kp = K + (size_t)(b * 3) * imgstep;
  const _Float16* Vp = V + (size_t)(b * 3) * imgstep;

  // ---- prefetch frame 0 (in flight during qfrag/qe setup) ----
  f16x4 kpre[6], vpre[6];
#pragma unroll
  for (int it = 0; it < 6; ++it) {
    kpre[it] = *(const f16x4*)&Kp[poff[it]];
    vpre[it] = *(const f16x4*)&Vp[poff[it]];
  }

  // Q fragments (pre-scaled, spatial emb folded by qkv kernel)
  f16x4 qfrag[2];
#pragma unroll
  for (int h = 0; h < 2; ++h)
    qfrag[h] = *(const f16x4*)&Q[(size_t)tok * CK_ + chb + h * 16 + 4 * g];

  // qe[s][q] = Qs . emb_s via MFMA -> per-wave-private LDS slice (no barrier)
#pragma unroll
  for (int h = 0; h < 2; ++h) {
#pragma unroll
    for (int mt = 0; mt < 2; ++mt) {
      const f16x4 a = *(const f16x4*)&spH[(size_t)(mt * 16 + l15) * 128 + chb + h * 16 + 4 * g];
      f32x4 c = {0.f, 0.f, 0.f, 0.f};
      c = mfma16(a, qfrag[h], c);
      if (mt == 0 || g < 3) {       // s = mt*16+4g+0..3 < 28 only
        f16x4 q4;
        q4[0] = (_Float16)c[0]; q4[1] = (_Float16)c[1];
        q4[2] = (_Float16)c[2]; q4[3] = (_Float16)c[3];
        *(f16x4*)&qe_s[(q_glob * 2 + h) * 28 + mt * 16 + 4 * g] = q4;
      }
    }
  }

  f32x4 o_acc[2];
  float l_acc[2];
#pragma unroll
  for (int h = 0; h < 2; ++h) { o_acc[h] = (f32x4){0.f, 0.f, 0.f, 0.f}; l_acc[h] = 0.f; }

#pragma unroll
  for (int t = 0; t < 3; ++t) {
    if (t) __syncthreads();           // prev-frame reads done before restage
    // regs -> LDS (prefetched)
#pragma unroll
    for (int it = 0; it < 6; ++it) {
      *(f16x4*)&K_s[ldoff[it]] = kpre[it];
      *(f16x4*)&V_s[ldoff[it]] = vpre[it];
    }
    __syncthreads();                  // staging visible
    // issue next frame's loads BEFORE compute -> latency hidden
    if (t < 2) {
      const _Float16* Kt = Kp + (size_t)(t + 1) * imgstep;
      const _Float16* Vt = Vp + (size_t)(t + 1) * imgstep;
#pragma unroll
      for (int it = 0; it < 6; ++it) {
        kpre[it] = *(const f16x4*)&Kt[poff[it]];
        vpre[it] = *(const f16x4*)&Vt[poff[it]];
      }
    }

    __builtin_amdgcn_s_setprio(1);
    f16x4 wfr[2][6];
#pragma unroll
    for (int h = 0; h < 2; ++h) {
#pragma unroll
      for (int jj = 0; jj < 6; ++jj) {
        const int nt = rymin + jj;
        const f16x4 a = *(const f16x4*)&K_s[(nt * 16 + l15) * 44 + h * 16 + 4 * g];
        f32x4 c = {0.f, 0.f, 0.f, 0.f};
        c = mfma16(a, qfrag[h], c);
        const int dyp = nt - myryc + 2;
        const bool vy = (unsigned)dyp <= 4u;
        const int s0 = dyp * 5 + dxpbase;
        const int qbase = (q_glob * 2 + h) * 28;
        float p0, p1, p2, p3;
#pragma unroll
        for (int i = 0; i < 4; ++i) {
          const int si = min(max(s0 + i, 0), 24);
          const float qv = (float)qe_s[qbase + si];
          float sc = c[i] + qv;
          const bool vi = vy && ((unsigned)(dxpbase + i) <= 4u);
          sc = vi ? sc : -1.0e30f;
          const float p = __builtin_amdgcn_exp2f(sc);
          l_acc[h] += p;
          if (i == 0) p0 = p; else if (i == 1) p1 = p; else if (i == 2) p2 = p; else p3 = p;
        }
        f16x4 wf;
        wf[0] = (_Float16)p0; wf[1] = (_Float16)p1;
        wf[2] = (_Float16)p2; wf[3] = (_Float16)p3;
        wfr[h][jj] = wf;
      }
    }

    // PV: o = w . V  (w C-frag reused as A-frag; V row-major B-frags)
#pragma unroll
    for (int h = 0; h < 2; ++h) {
#pragma unroll
      for (int jj = 0; jj < 6; ++jj) {
        const int nt = rymin + jj;
        f16x4 bv;
#pragma unroll
        for (int i = 0; i < 4; ++i)
          bv[i] = V_s[(nt * 16 + 4 * g + i) * 44 + h * 16 + l15];
        o_acc[h] = mfma16(wfr[h][jj], bv, o_acc[h]);
      }
    }
    __builtin_amdgcn_s_setprio(0);
  }

  // normalize: l lives per (q=l15); o lives per (q=4g+i, ch=l15) -> via LDS
#pragma unroll
  for (int h = 0; h < 2; ++h) {
    float lt = l_acc[h];
    lt += __shfl_xor(lt, 16);
    lt += __shfl_xor(lt, 32);
    if (l < 16) l_s[wv][h][l15] = 1.f / lt;
  }
  __syncthreads();
#pragma unroll
  for (int h = 0; h < 2; ++h) {
#pragma unroll
    for (int i = 0; i < 4; ++i) {
      const int q = 4 * g + i;
      const float inv = l_s[wv][h][q];
      const int qtok = tokbase + (2 * wv + (q >> 3)) * 128 + (q & 7);
      ck[(size_t)qtok * CK_ + chb + h * 16 + l15] = (_Float16)(o_acc[h][i] * inv);
    }
  }
}

// ---------------------------------------------------------------------------
// Kernel C: out = ck @ Wo via MFMA. Block = 128 tokens; wave = 2 N-tiles x 8
// token-tiles. ck_s stride 152 (bank spread ~2/bank).
// ---------------------------------------------------------------------------
__global__ __launch_bounds__(256) void out_mfma(
    const _Float16* __restrict__ ck, const _Float16* __restrict__ WoT,
    float* __restrict__ out)
{
  __shared__ __align__(16) _Float16 ck_s[128][152];
  const int tid = threadIdx.x;
  const int tok0 = blockIdx.x * 128;

  for (int i = tid; i < 128 * 16; i += 256) {
    const int tk = i >> 4, cg = i & 15;
    *(f16x8*)&ck_s[tk][cg * 8] = *(const f16x8*)&ck[(size_t)(tok0 + tk) * C_ + cg * 8];
  }
  __syncthreads();

  const int l = tid & 63, w = tid >> 6, l15 = l & 15, g = l >> 4;

  f32x4 acc[2][8];
#pragma unroll
  for (int j = 0; j < 2; ++j)
#pragma unroll
    for (int tt = 0; tt < 8; ++tt) acc[j][tt] = (f32x4){0.f, 0.f, 0.f, 0.f};

  for (int kc = 0; kc < 8; ++kc) {
    const int ko = kc * 16 + 4 * g;
    f16x4 bfr[8];
#pragma unroll
    for (int tt = 0; tt < 8; ++tt)
      bfr[tt] = *(const f16x4*)&ck_s[tt * 16 + l15][ko];
#pragma unroll
    for (int j = 0; j < 2; ++j) {
      const f16x4 a = *(const f16x4*)&WoT[(size_t)((w * 2 + j) * 16 + l15) * 128 + ko];
#pragma unroll
      for (int tt = 0; tt < 8; ++tt)
        acc[j][tt] = mfma16(a, bfr[tt], acc[j][tt]);
    }
  }

#pragma unroll
  for (int j = 0; j < 2; ++j) {
    const int ch0 = (w * 2 + j) * 16 + 4 * g;
#pragma unroll
    for (int tt = 0; tt < 8; ++tt) {
      const int tok = tok0 + tt * 16 + l15;
      float4 ov;
      ov.x = acc[j][tt][0]; ov.y = acc[j][tt][1];
      ov.z = acc[j][tt][2]; ov.w = acc[j][tt][3];
      *(float4*)&out[(size_t)tok * C_ + ch0] = ov;
    }
  }
}

// ---------------------------------------------------------------------------
extern "C" void kernel_launch(void* const* d_in, const int* in_sizes, int n_in,
                              void* d_out, int out_size, void* d_ws, size_t ws_size,
                              hipStream_t stream) {
    const float* values      = (const float*)d_in[0];
    const float* Wq          = (const float*)d_in[1];
    const float* Wk          = (const float*)d_in[2];
    const float* Wv          = (const float*)d_in[3];
    const float* Wo          = (const float*)d_in[4];
    const float* temp_emb    = (const float*)d_in[5];
    const float* spatial_emb = (const float*)d_in[6];
    float* out = (float*)d_out;

    const size_t NC = (size_t)NTOK * CK_;
    _Float16* Qh  = (_Float16*)d_ws;
    _Float16* Kh  = Qh  + NC;
    _Float16* Vh  = Kh  + NC;
    _Float16* ckh = Vh  + NC;
    _Float16* WT  = ckh + NC;          // [384][128]
    _Float16* WoT = WT  + 49152;       // [128][128]
    _Float16* spH = WoT + 16384;       // [32][128]
    float*    tv  = (float*)(spH + 4096);  // [3][128]

    prep<<<274, 256, 0, stream>>>(Wq, Wk, Wv, Wo, spatial_emb, temp_emb,
                                  WT, WoT, spH, tv);
    qkv_mfma<<<NTOK / 64, 256, 0, stream>>>(values, WT, temp_emb, spatial_emb,
                                            tv, Qh, Kh, Vh);
    attn_mfma<<<6144, 256, 0, stream>>>(Qh, Kh, Vh, spH, ckh);
    out_mfma<<<NTOK / 128, 256, 0, stream>>>(ckh, WoT, out);
}